// Round 1
// baseline (5500.945 us; speedup 1.0000x reference)
//
#include <hip/hip_runtime.h>
#include <math.h>

#define BSZ 4
#define NXN 4096
#define NPARP 5
#define HD 128
#define NLAY 6
#define KNN 16
#define DTC 0.1f
#define EPSC 1e-5f

__device__ __forceinline__ float swishf(float x) {
    return x / (1.0f + __expf(-x));
}

// ---------------- grid min/max per batch ----------------
__global__ void kminmax(const float* __restrict__ grid, float* __restrict__ gmm) {
    int b = blockIdx.x;
    int t = threadIdx.x;
    float mnx = 1e30f, mxx = -1e30f, mny = 1e30f, mxy = -1e30f;
    for (int n = t; n < NXN; n += 256) {
        float x = grid[(b * NXN + n) * 2 + 0];
        float y = grid[(b * NXN + n) * 2 + 1];
        mnx = fminf(mnx, x); mxx = fmaxf(mxx, x);
        mny = fminf(mny, y); mxy = fmaxf(mxy, y);
    }
    __shared__ float s[4][256];
    s[0][t] = mnx; s[1][t] = mxx; s[2][t] = mny; s[3][t] = mxy;
    __syncthreads();
    for (int off = 128; off > 0; off >>= 1) {
        if (t < off) {
            s[0][t] = fminf(s[0][t], s[0][t + off]);
            s[1][t] = fmaxf(s[1][t], s[1][t + off]);
            s[2][t] = fminf(s[2][t], s[2][t + off]);
            s[3][t] = fmaxf(s[3][t], s[3][t + off]);
        }
        __syncthreads();
    }
    if (t == 0) {
        gmm[b * 4 + 0] = s[0][0];
        gmm[b * 4 + 1] = s[1][0];
        gmm[b * 4 + 2] = s[2][0];
        gmm[b * 4 + 3] = s[3][0];
    }
}

// ---------------- pos + sq ----------------
__global__ void kpos(const float* __restrict__ grid, const float* __restrict__ gmm,
                     float* __restrict__ pos, float* __restrict__ sq) {
    int g = blockIdx.x * 256 + threadIdx.x;
    if (g >= BSZ * NXN) return;
    int b = g >> 12;
    float gx = grid[g * 2], gy = grid[g * 2 + 1];
    float px = (gx - gmm[b * 4 + 0]) / (gmm[b * 4 + 1] - gmm[b * 4 + 0]);
    float py = (gy - gmm[b * 4 + 2]) / (gmm[b * 4 + 3] - gmm[b * 4 + 2]);
    pos[g * 2] = px; pos[g * 2 + 1] = py;
    sq[g] = __fadd_rn(__fmul_rn(px, px), __fmul_rn(py, py));
}

// ---------------- KNN (top-16 smallest d2, ties -> lower index) ----------------
__global__ __launch_bounds__(256) void kknn(const float* __restrict__ pos,
                                            const float* __restrict__ sq,
                                            int* __restrict__ idxw) {
    __shared__ float sx[NXN], sy[NXN], ss[NXN];
    int b = blockIdx.x >> 4;
    int chunk = blockIdx.x & 15;
    int t = threadIdx.x;
    for (int n = t; n < NXN; n += 256) {
        sx[n] = pos[(b * NXN + n) * 2];
        sy[n] = pos[(b * NXN + n) * 2 + 1];
        ss[n] = sq[b * NXN + n];
    }
    __syncthreads();
    int i = chunk * 256 + t;
    float xi = sx[i], yi = sy[i], sqi = ss[i];
    float bd[KNN]; int bj[KNN];
#pragma unroll
    for (int s0 = 0; s0 < KNN; s0++) { bd[s0] = 1e30f; bj[s0] = 0x7fffffff; }
    float wd = 1e30f; int wj = 0x7fffffff; int wslot = 0;
    for (int j = 0; j < NXN; j++) {
        float s12 = __fadd_rn(sqi, ss[j]);
        float dot = __fadd_rn(__fmul_rn(xi, sx[j]), __fmul_rn(yi, sy[j]));
        float d2 = __fadd_rn(s12, -(2.0f * dot));
        if (j == i) d2 = 1e10f;
        bool better = (d2 < wd) || (d2 == wd && j < wj);
        if (better) {
#pragma unroll
            for (int s0 = 0; s0 < KNN; s0++) {
                if (s0 == wslot) { bd[s0] = d2; bj[s0] = j; }
            }
            wd = bd[0]; wj = bj[0]; wslot = 0;
#pragma unroll
            for (int s0 = 1; s0 < KNN; s0++) {
                bool worse = (bd[s0] > wd) || (bd[s0] == wd && bj[s0] > wj);
                if (worse) { wd = bd[s0]; wj = bj[s0]; wslot = s0; }
            }
        }
    }
#pragma unroll
    for (int s0 = 0; s0 < KNN; s0++) idxw[(b * NXN + i) * KNN + s0] = bj[s0];
}

// ---------------- embedding MLP: [u,pos,params](8) -> 128 -> 128 ----------------
__global__ __launch_bounds__(128) void kembed(const float* __restrict__ inputs,
                                              const float* __restrict__ pos,
                                              const float* __restrict__ params,
                                              const float* __restrict__ w1,
                                              const float* __restrict__ b1,
                                              const float* __restrict__ w2,
                                              const float* __restrict__ b2,
                                              float* __restrict__ f) {
    __shared__ float sh[HD];
    int t = threadIdx.x;
    int g = blockIdx.x;
    float rw1[8];
#pragma unroll
    for (int k = 0; k < 8; k++) rw1[k] = w1[k * HD + t];
    float u = inputs[g];
    float px = pos[g * 2], py = pos[g * 2 + 1];
    float a = b1[t] + u * rw1[0] + px * rw1[1] + py * rw1[2];
#pragma unroll
    for (int j = 0; j < NPARP; j++) a += params[g * NPARP + j] * rw1[3 + j];
    sh[t] = swishf(a);
    __syncthreads();
    float a2 = b2[t];
    for (int k = 0; k < HD; k++) a2 += sh[k] * w2[k * HD + t];
    f[g * HD + t] = swishf(a2);
}

// ---------------- fused message + aggregate + update (one node per block) ----------------
__global__ __launch_bounds__(128) void kmsg(const float* __restrict__ f,
                                            float* __restrict__ fnew,
                                            const float* __restrict__ inputs,
                                            const float* __restrict__ pos,
                                            const float* __restrict__ params,
                                            const int* __restrict__ idxw,
                                            const float* __restrict__ W1,
                                            const float* __restrict__ B1,
                                            const float* __restrict__ W2,
                                            const float* __restrict__ B2,
                                            const float* __restrict__ U1,
                                            const float* __restrict__ UB1,
                                            const float* __restrict__ U2,
                                            const float* __restrict__ UB2) {
    __shared__ float fi[HD];
    __shared__ float fjs[KNN][HD];
    __shared__ float hs[KNN][HD];
    __shared__ float aggs[HD];
    __shared__ float hus[HD];
    __shared__ float dus[KNN], dpxs[KNN], dpys[KNN], vars[8];
    __shared__ int idxs[KNN];
    int c = threadIdx.x;
    int bn = blockIdx.x;
    int b = bn >> 12;
    if (c < KNN) idxs[c] = idxw[bn * KNN + c];
    fi[c] = f[bn * HD + c];
    if (c < NPARP) vars[c] = params[bn * NPARP + c];
    __syncthreads();
    if (c < KNN) {
        int gj = (b << 12) + idxs[c];
        dus[c] = inputs[bn] - inputs[gj];
        dpxs[c] = pos[bn * 2] - pos[gj * 2];
        dpys[c] = pos[bn * 2 + 1] - pos[gj * 2 + 1];
    }
#pragma unroll 4
    for (int e = 0; e < KNN; e++) {
        int gj = (b << 12) + idxs[e];
        fjs[e][c] = f[gj * HD + c];
    }
    __syncthreads();

    // ---- mm1: m = [f_i, f_j, du, dpos, var] @ W1 ; factor out edge-invariant part
    float com = B1[c];
    for (int k = 0; k < HD; k++) com += fi[k] * W1[k * HD + c];
#pragma unroll
    for (int j = 0; j < NPARP; j++) com += vars[j] * W1[(259 + j) * HD + c];
    float wdu = W1[256 * HD + c], wdx = W1[257 * HD + c], wdy = W1[258 * HD + c];
    float acc[KNN];
#pragma unroll
    for (int e = 0; e < KNN; e++)
        acc[e] = com + dus[e] * wdu + dpxs[e] * wdx + dpys[e] * wdy;
    for (int k = 0; k < HD; k++) {
        float w = W1[(HD + k) * HD + c];
#pragma unroll
        for (int e = 0; e < KNN; e++) acc[e] += fjs[e][k] * w;
    }
#pragma unroll
    for (int e = 0; e < KNN; e++) hs[e][c] = swishf(acc[e]);
    __syncthreads();

    // ---- mm2 + mean over edges
    float bb = B2[c];
    float acc2[KNN];
#pragma unroll
    for (int e = 0; e < KNN; e++) acc2[e] = bb;
    for (int k = 0; k < HD; k++) {
        float w = W2[k * HD + c];
#pragma unroll
        for (int e = 0; e < KNN; e++) acc2[e] += hs[e][k] * w;
    }
    float ag = 0.0f;
#pragma unroll
    for (int e = 0; e < KNN; e++) ag += swishf(acc2[e]);
    aggs[c] = ag * 0.0625f;
    __syncthreads();

    // ---- update MLP: [f, agg, params](261) -> 128 -> 128
    float a = UB1[c];
    for (int k = 0; k < HD; k++) a += fi[k] * U1[k * HD + c];
    for (int k = 0; k < HD; k++) a += aggs[k] * U1[(HD + k) * HD + c];
#pragma unroll
    for (int j = 0; j < NPARP; j++) a += vars[j] * U1[(256 + j) * HD + c];
    hus[c] = swishf(a);
    __syncthreads();
    float a2 = UB2[c];
    for (int k = 0; k < HD; k++) a2 += hus[k] * U2[k * HD + c];
    fnew[bn * HD + c] = fi[c] + swishf(a2);
}

// ---------------- instance norm: stats (partial), finalize, apply ----------------
__global__ __launch_bounds__(256) void kstats(const float* __restrict__ fnew,
                                              float* __restrict__ p1, float* __restrict__ p2) {
    int blk = blockIdx.x;
    int b = blk >> 3;
    int ch = blk & 7;
    int t = threadIdx.x;
    int c = t & 127;
    int half = t >> 7;
    int nbase = ch * 512;
    float s1 = 0.0f, s2 = 0.0f;
    for (int n = half; n < 512; n += 2) {
        float v = fnew[((b * NXN) + (nbase + n)) * HD + c];
        s1 += v; s2 += v * v;
    }
    __shared__ float r1[256], r2[256];
    r1[t] = s1; r2[t] = s2;
    __syncthreads();
    if (half == 0) {
        s1 += r1[t + 128]; s2 += r2[t + 128];
        p1[blk * HD + c] = s1;
        p2[blk * HD + c] = s2;
    }
}

__global__ void kfinal(const float* __restrict__ p1, const float* __restrict__ p2,
                       float* __restrict__ mean, float* __restrict__ inv) {
    int g = blockIdx.x * 256 + threadIdx.x;
    if (g >= BSZ * HD) return;
    int b = g >> 7;
    int c = g & 127;
    float s1 = 0.0f, s2 = 0.0f;
#pragma unroll
    for (int ch = 0; ch < 8; ch++) {
        s1 += p1[(b * 8 + ch) * HD + c];
        s2 += p2[(b * 8 + ch) * HD + c];
    }
    float m = s1 * (1.0f / NXN);
    float v = s2 * (1.0f / NXN) - m * m;
    mean[g] = m;
    inv[g] = rsqrtf(v + EPSC);
}

__global__ void kapply(const float* __restrict__ fnew, const float* __restrict__ mean,
                       const float* __restrict__ inv, float* __restrict__ f) {
    int g = blockIdx.x * 256 + threadIdx.x;
    int b = g >> 19;
    int c = g & 127;
    f[g] = (fnew[g] - mean[b * HD + c]) * inv[b * HD + c];
}

// ---------------- output head ----------------
__global__ __launch_bounds__(64) void khead(const float* __restrict__ f,
                                            const float* __restrict__ inputs,
                                            const float* __restrict__ ow1,
                                            const float* __restrict__ ob1,
                                            const float* __restrict__ ow2,
                                            const float* __restrict__ ob2,
                                            float* __restrict__ out) {
    int bn = blockIdx.x;
    int c = threadIdx.x;
    float a = ob1[c];
    for (int k = 0; k < HD; k++) a += f[bn * HD + k] * ow1[k * 64 + c];
    float v = swishf(a) * ow2[c];
#pragma unroll
    for (int off = 32; off > 0; off >>= 1) v += __shfl_down(v, off);
    if (c == 0) out[bn] = inputs[bn] + DTC * (v + ob2[0]);
}

extern "C" void kernel_launch(void* const* d_in, const int* in_sizes, int n_in,
                              void* d_out, int out_size, void* d_ws, size_t ws_size,
                              hipStream_t stream) {
    const float* inputs = (const float*)d_in[0];
    const float* params = (const float*)d_in[1];
    // d_in[2] = mask (unused)
    const float* grid   = (const float*)d_in[3];
    const float* emb_w1 = (const float*)d_in[4];
    const float* emb_b1 = (const float*)d_in[5];
    const float* emb_w2 = (const float*)d_in[6];
    const float* emb_b2 = (const float*)d_in[7];
    const float* mw1 = (const float*)d_in[8];
    const float* mb1 = (const float*)d_in[9];
    const float* mw2 = (const float*)d_in[10];
    const float* mb2 = (const float*)d_in[11];
    const float* uw1 = (const float*)d_in[12];
    const float* ub1 = (const float*)d_in[13];
    const float* uw2 = (const float*)d_in[14];
    const float* ub2 = (const float*)d_in[15];
    const float* ow1 = (const float*)d_in[16];
    const float* ob1 = (const float*)d_in[17];
    const float* ow2 = (const float*)d_in[18];
    const float* ob2 = (const float*)d_in[19];
    float* out = (float*)d_out;

    float* ws  = (float*)d_ws;
    float* pos = ws;                   // BS*NX*2
    float* sq  = pos + BSZ * NXN * 2;  // BS*NX
    float* f   = sq + BSZ * NXN;       // BS*NX*H
    float* fnew = f + BSZ * NXN * HD;  // BS*NX*H
    float* mean = fnew + BSZ * NXN * HD;  // BS*H
    float* inv  = mean + BSZ * HD;        // BS*H
    float* p1   = inv + BSZ * HD;         // BS*8*H
    float* p2   = p1 + BSZ * 8 * HD;      // BS*8*H
    float* gmm  = p2 + BSZ * 8 * HD;      // 16
    int* idxw   = (int*)(gmm + 16);       // BS*NX*K ints

    kminmax<<<BSZ, 256, 0, stream>>>(grid, gmm);
    kpos<<<(BSZ * NXN) / 256, 256, 0, stream>>>(grid, gmm, pos, sq);
    kknn<<<BSZ * (NXN / 256), 256, 0, stream>>>(pos, sq, idxw);
    kembed<<<BSZ * NXN, 128, 0, stream>>>(inputs, pos, params,
                                          emb_w1, emb_b1, emb_w2, emb_b2, f);
    for (int l = 0; l < NLAY; l++) {
        kmsg<<<BSZ * NXN, 128, 0, stream>>>(f, fnew, inputs, pos, params, idxw,
                                            mw1 + l * 264 * HD, mb1 + l * HD,
                                            mw2 + l * HD * HD, mb2 + l * HD,
                                            uw1 + l * 261 * HD, ub1 + l * HD,
                                            uw2 + l * HD * HD, ub2 + l * HD);
        kstats<<<BSZ * 8, 256, 0, stream>>>(fnew, p1, p2);
        kfinal<<<2, 256, 0, stream>>>(p1, p2, mean, inv);
        kapply<<<(BSZ * NXN * HD) / 256, 256, 0, stream>>>(fnew, mean, inv, f);
    }
    khead<<<BSZ * NXN, 64, 0, stream>>>(f, inputs, ow1, ob1, ow2, ob2, out);
}

// Round 2
// 3512.938 us; speedup vs baseline: 1.5659x; 1.5659x over previous
//
#include <hip/hip_runtime.h>
#include <math.h>

#define BSZ 4
#define NXN 4096
#define NPARP 5
#define HD 128
#define NLAY 6
#define KNN 16
#define DTC 0.1f
#define EPSC 1e-5f
#define NJC 8
#define JCH (NXN / NJC)
#define NN (BSZ * NXN)

__device__ __forceinline__ float swishf(float x) {
    return x / (1.0f + __expf(-x));
}

// ---------------- grid min/max per batch ----------------
__global__ void kminmax(const float* __restrict__ grid, float* __restrict__ gmm) {
    int b = blockIdx.x;
    int t = threadIdx.x;
    float mnx = 1e30f, mxx = -1e30f, mny = 1e30f, mxy = -1e30f;
    for (int n = t; n < NXN; n += 256) {
        float x = grid[(b * NXN + n) * 2 + 0];
        float y = grid[(b * NXN + n) * 2 + 1];
        mnx = fminf(mnx, x); mxx = fmaxf(mxx, x);
        mny = fminf(mny, y); mxy = fmaxf(mxy, y);
    }
    __shared__ float s[4][256];
    s[0][t] = mnx; s[1][t] = mxx; s[2][t] = mny; s[3][t] = mxy;
    __syncthreads();
    for (int off = 128; off > 0; off >>= 1) {
        if (t < off) {
            s[0][t] = fminf(s[0][t], s[0][t + off]);
            s[1][t] = fmaxf(s[1][t], s[1][t + off]);
            s[2][t] = fminf(s[2][t], s[2][t + off]);
            s[3][t] = fmaxf(s[3][t], s[3][t + off]);
        }
        __syncthreads();
    }
    if (t == 0) {
        gmm[b * 4 + 0] = s[0][0];
        gmm[b * 4 + 1] = s[1][0];
        gmm[b * 4 + 2] = s[2][0];
        gmm[b * 4 + 3] = s[3][0];
    }
}

// ---------------- pos + sq ----------------
__global__ void kpos(const float* __restrict__ grid, const float* __restrict__ gmm,
                     float* __restrict__ pos, float* __restrict__ sq) {
    int g = blockIdx.x * 256 + threadIdx.x;
    if (g >= NN) return;
    int b = g >> 12;
    float gx = grid[g * 2], gy = grid[g * 2 + 1];
    float px = (gx - gmm[b * 4 + 0]) / (gmm[b * 4 + 1] - gmm[b * 4 + 0]);
    float py = (gy - gmm[b * 4 + 2]) / (gmm[b * 4 + 3] - gmm[b * 4 + 2]);
    pos[g * 2] = px; pos[g * 2 + 1] = py;
    sq[g] = __fadd_rn(__fmul_rn(px, px), __fmul_rn(py, py));
}

// ---------------- KNN phase 1: per (node, j-chunk) register top-16 ----------------
__global__ __launch_bounds__(256) void kknn1(const float* __restrict__ pos,
                                             const float* __restrict__ sq,
                                             float* __restrict__ cd,
                                             int* __restrict__ cj) {
    __shared__ float2 sxy[JCH];
    __shared__ float ss[JCH];
    int blk = blockIdx.x;
    int ib = blk & 15;          // NXN/256 = 16
    int jc = (blk >> 4) & 7;    // NJC = 8
    int b  = blk >> 7;
    int t = threadIdx.x;
    for (int n = t; n < JCH; n += 256) {
        int j = jc * JCH + n;
        sxy[n] = *(const float2*)&pos[(b * NXN + j) * 2];
        ss[n] = sq[b * NXN + j];
    }
    __syncthreads();
    int i = ib * 256 + t;
    float2 pi = *(const float2*)&pos[(b * NXN + i) * 2];
    float sqi = sq[b * NXN + i];
    float bd[KNN]; int bj[KNN];
#pragma unroll
    for (int s = 0; s < KNN; s++) { bd[s] = 1e30f; bj[s] = -1; }
    float wd = 1e30f; int wslot = 0;
    int jbase = jc * JCH;
    for (int n = 0; n < JCH; n++) {
        float2 pj = sxy[n];
        float d2 = fmaf(-2.0f, fmaf(pi.x, pj.x, pi.y * pj.y), sqi + ss[n]);
        int j = jbase + n;
        if ((d2 < wd) && (j != i)) {
#pragma unroll
            for (int s = 0; s < KNN; s++) {
                if (s == wslot) { bd[s] = d2; bj[s] = j; }
            }
            wd = bd[0]; wslot = 0;
#pragma unroll
            for (int s = 1; s < KNN; s++) {
                bool w = bd[s] > wd;
                wd = w ? bd[s] : wd;
                wslot = w ? s : wslot;
            }
        }
    }
    int node = b * NXN + i;
#pragma unroll
    for (int s = 0; s < KNN; s++) {
        cd[(jc * KNN + s) * NN + node] = bd[s];
        cj[(jc * KNN + s) * NN + node] = bj[s];
    }
}

// ---------------- KNN phase 2: merge 8x16 candidates -> final 16 ----------------
__global__ __launch_bounds__(256) void kknn2(const float* __restrict__ cd,
                                             const int* __restrict__ cj,
                                             int* __restrict__ idxw) {
    int g = blockIdx.x * 256 + threadIdx.x;
    float bd[KNN]; int bj[KNN];
#pragma unroll
    for (int s = 0; s < KNN; s++) { bd[s] = 1e30f; bj[s] = -1; }
    float wd = 1e30f; int wslot = 0;
    for (int c = 0; c < NJC * KNN; c++) {
        float d2 = cd[c * NN + g];
        int j = cj[c * NN + g];
        if (d2 < wd) {
#pragma unroll
            for (int s = 0; s < KNN; s++) {
                if (s == wslot) { bd[s] = d2; bj[s] = j; }
            }
            wd = bd[0]; wslot = 0;
#pragma unroll
            for (int s = 1; s < KNN; s++) {
                bool w = bd[s] > wd;
                wd = w ? bd[s] : wd;
                wslot = w ? s : wslot;
            }
        }
    }
#pragma unroll
    for (int s = 0; s < KNN; s++) idxw[g * KNN + s] = bj[s];
}

// ---------------- embedding MLP: [u,pos,params](8) -> 128 -> 128 ----------------
__global__ __launch_bounds__(128) void kembed(const float* __restrict__ inputs,
                                              const float* __restrict__ pos,
                                              const float* __restrict__ params,
                                              const float* __restrict__ w1,
                                              const float* __restrict__ b1,
                                              const float* __restrict__ w2,
                                              const float* __restrict__ b2,
                                              float* __restrict__ f) {
    __shared__ __align__(16) float sh[HD];
    int t = threadIdx.x;
    int g = blockIdx.x;
    float rw1[8];
#pragma unroll
    for (int k = 0; k < 8; k++) rw1[k] = w1[k * HD + t];
    float u = inputs[g];
    float px = pos[g * 2], py = pos[g * 2 + 1];
    float a = b1[t] + u * rw1[0] + px * rw1[1] + py * rw1[2];
#pragma unroll
    for (int j = 0; j < NPARP; j++) a += params[g * NPARP + j] * rw1[3 + j];
    sh[t] = swishf(a);
    __syncthreads();
    float a2 = b2[t];
    for (int k = 0; k < HD; k += 4) {
        float4 s4 = *(const float4*)&sh[k];
        a2 = fmaf(s4.x, w2[(k + 0) * HD + t], a2);
        a2 = fmaf(s4.y, w2[(k + 1) * HD + t], a2);
        a2 = fmaf(s4.z, w2[(k + 2) * HD + t], a2);
        a2 = fmaf(s4.w, w2[(k + 3) * HD + t], a2);
    }
    f[g * HD + t] = swishf(a2);
}

// ---------------- fused message + aggregate + update (one node per block) ----------------
__global__ __launch_bounds__(128) void kmsg(const float* __restrict__ f,
                                            float* __restrict__ fnew,
                                            const float* __restrict__ inputs,
                                            const float* __restrict__ pos,
                                            const float* __restrict__ params,
                                            const int* __restrict__ idxw,
                                            const float* __restrict__ W1,
                                            const float* __restrict__ B1,
                                            const float* __restrict__ W2,
                                            const float* __restrict__ B2,
                                            const float* __restrict__ U1,
                                            const float* __restrict__ UB1,
                                            const float* __restrict__ U2,
                                            const float* __restrict__ UB2) {
    __shared__ __align__(16) float fi[HD];
    __shared__ __align__(16) float fjs[KNN][HD];
    __shared__ __align__(16) float hs[KNN][HD];
    __shared__ __align__(16) float aggs[HD];
    __shared__ __align__(16) float hus[HD];
    __shared__ float dus[KNN], dpxs[KNN], dpys[KNN], vars[8];
    __shared__ int idxs[KNN];
    int c = threadIdx.x;
    int bn = blockIdx.x;
    int b = bn >> 12;
    if (c < KNN) idxs[c] = idxw[bn * KNN + c];
    fi[c] = f[bn * HD + c];
    if (c < NPARP) vars[c] = params[bn * NPARP + c];
    __syncthreads();
    if (c < KNN) {
        int gj = (b << 12) + idxs[c];
        dus[c] = inputs[bn] - inputs[gj];
        dpxs[c] = pos[bn * 2] - pos[gj * 2];
        dpys[c] = pos[bn * 2 + 1] - pos[gj * 2 + 1];
    }
#pragma unroll 4
    for (int e = 0; e < KNN; e++) {
        int gj = (b << 12) + idxs[e];
        fjs[e][c] = f[gj * HD + c];
    }
    __syncthreads();

    // ---- mm1: m = [f_i, f_j, du, dpos, var] @ W1 ; factor out edge-invariant part
    float com = B1[c];
    for (int k = 0; k < HD; k += 4) {
        float4 f4 = *(const float4*)&fi[k];
        com = fmaf(f4.x, W1[(k + 0) * HD + c], com);
        com = fmaf(f4.y, W1[(k + 1) * HD + c], com);
        com = fmaf(f4.z, W1[(k + 2) * HD + c], com);
        com = fmaf(f4.w, W1[(k + 3) * HD + c], com);
    }
#pragma unroll
    for (int j = 0; j < NPARP; j++) com += vars[j] * W1[(259 + j) * HD + c];
    float wdu = W1[256 * HD + c], wdx = W1[257 * HD + c], wdy = W1[258 * HD + c];
    float acc[KNN];
#pragma unroll
    for (int e = 0; e < KNN; e++)
        acc[e] = com + dus[e] * wdu + dpxs[e] * wdx + dpys[e] * wdy;
    for (int k = 0; k < HD; k += 4) {
        float w0 = W1[(HD + k + 0) * HD + c];
        float w1 = W1[(HD + k + 1) * HD + c];
        float w2 = W1[(HD + k + 2) * HD + c];
        float w3 = W1[(HD + k + 3) * HD + c];
#pragma unroll
        for (int e = 0; e < KNN; e++) {
            float4 fj = *(const float4*)&fjs[e][k];
            acc[e] = fmaf(fj.x, w0, acc[e]);
            acc[e] = fmaf(fj.y, w1, acc[e]);
            acc[e] = fmaf(fj.z, w2, acc[e]);
            acc[e] = fmaf(fj.w, w3, acc[e]);
        }
    }
#pragma unroll
    for (int e = 0; e < KNN; e++) hs[e][c] = swishf(acc[e]);
    __syncthreads();

    // ---- mm2 + mean over edges
    float bb = B2[c];
    float acc2[KNN];
#pragma unroll
    for (int e = 0; e < KNN; e++) acc2[e] = bb;
    for (int k = 0; k < HD; k += 4) {
        float w0 = W2[(k + 0) * HD + c];
        float w1 = W2[(k + 1) * HD + c];
        float w2 = W2[(k + 2) * HD + c];
        float w3 = W2[(k + 3) * HD + c];
#pragma unroll
        for (int e = 0; e < KNN; e++) {
            float4 h4 = *(const float4*)&hs[e][k];
            acc2[e] = fmaf(h4.x, w0, acc2[e]);
            acc2[e] = fmaf(h4.y, w1, acc2[e]);
            acc2[e] = fmaf(h4.z, w2, acc2[e]);
            acc2[e] = fmaf(h4.w, w3, acc2[e]);
        }
    }
    float ag = 0.0f;
#pragma unroll
    for (int e = 0; e < KNN; e++) ag += swishf(acc2[e]);
    aggs[c] = ag * 0.0625f;
    __syncthreads();

    // ---- update MLP: [f, agg, params](261) -> 128 -> 128
    float a = UB1[c];
    for (int k = 0; k < HD; k += 4) {
        float4 f4 = *(const float4*)&fi[k];
        a = fmaf(f4.x, U1[(k + 0) * HD + c], a);
        a = fmaf(f4.y, U1[(k + 1) * HD + c], a);
        a = fmaf(f4.z, U1[(k + 2) * HD + c], a);
        a = fmaf(f4.w, U1[(k + 3) * HD + c], a);
    }
    for (int k = 0; k < HD; k += 4) {
        float4 g4 = *(const float4*)&aggs[k];
        a = fmaf(g4.x, U1[(HD + k + 0) * HD + c], a);
        a = fmaf(g4.y, U1[(HD + k + 1) * HD + c], a);
        a = fmaf(g4.z, U1[(HD + k + 2) * HD + c], a);
        a = fmaf(g4.w, U1[(HD + k + 3) * HD + c], a);
    }
#pragma unroll
    for (int j = 0; j < NPARP; j++) a += vars[j] * U1[(256 + j) * HD + c];
    hus[c] = swishf(a);
    __syncthreads();
    float a2 = UB2[c];
    for (int k = 0; k < HD; k += 4) {
        float4 h4 = *(const float4*)&hus[k];
        a2 = fmaf(h4.x, U2[(k + 0) * HD + c], a2);
        a2 = fmaf(h4.y, U2[(k + 1) * HD + c], a2);
        a2 = fmaf(h4.z, U2[(k + 2) * HD + c], a2);
        a2 = fmaf(h4.w, U2[(k + 3) * HD + c], a2);
    }
    fnew[bn * HD + c] = fi[c] + swishf(a2);
}

// ---------------- instance norm: stats (partial), finalize, apply ----------------
__global__ __launch_bounds__(256) void kstats(const float* __restrict__ fnew,
                                              float* __restrict__ p1, float* __restrict__ p2) {
    int blk = blockIdx.x;
    int b = blk >> 3;
    int ch = blk & 7;
    int t = threadIdx.x;
    int c = t & 127;
    int half = t >> 7;
    int nbase = ch * 512;
    float s1 = 0.0f, s2 = 0.0f;
    for (int n = half; n < 512; n += 2) {
        float v = fnew[((b * NXN) + (nbase + n)) * HD + c];
        s1 += v; s2 += v * v;
    }
    __shared__ float r1[256], r2[256];
    r1[t] = s1; r2[t] = s2;
    __syncthreads();
    if (half == 0) {
        s1 += r1[t + 128]; s2 += r2[t + 128];
        p1[blk * HD + c] = s1;
        p2[blk * HD + c] = s2;
    }
}

__global__ void kfinal(const float* __restrict__ p1, const float* __restrict__ p2,
                       float* __restrict__ mean, float* __restrict__ inv) {
    int g = blockIdx.x * 256 + threadIdx.x;
    if (g >= BSZ * HD) return;
    int b = g >> 7;
    int c = g & 127;
    float s1 = 0.0f, s2 = 0.0f;
#pragma unroll
    for (int ch = 0; ch < 8; ch++) {
        s1 += p1[(b * 8 + ch) * HD + c];
        s2 += p2[(b * 8 + ch) * HD + c];
    }
    float m = s1 * (1.0f / NXN);
    float v = s2 * (1.0f / NXN) - m * m;
    mean[g] = m;
    inv[g] = rsqrtf(v + EPSC);
}

__global__ void kapply(const float* __restrict__ fnew, const float* __restrict__ mean,
                       const float* __restrict__ inv, float* __restrict__ f) {
    int g = blockIdx.x * 256 + threadIdx.x;
    int b = g >> 19;
    int c = g & 127;
    f[g] = (fnew[g] - mean[b * HD + c]) * inv[b * HD + c];
}

// ---------------- output head ----------------
__global__ __launch_bounds__(64) void khead(const float* __restrict__ f,
                                            const float* __restrict__ inputs,
                                            const float* __restrict__ ow1,
                                            const float* __restrict__ ob1,
                                            const float* __restrict__ ow2,
                                            const float* __restrict__ ob2,
                                            float* __restrict__ out) {
    int bn = blockIdx.x;
    int c = threadIdx.x;
    float a = ob1[c];
    for (int k = 0; k < HD; k++) a += f[bn * HD + k] * ow1[k * 64 + c];
    float v = swishf(a) * ow2[c];
#pragma unroll
    for (int off = 32; off > 0; off >>= 1) v += __shfl_down(v, off);
    if (c == 0) out[bn] = inputs[bn] + DTC * (v + ob2[0]);
}

extern "C" void kernel_launch(void* const* d_in, const int* in_sizes, int n_in,
                              void* d_out, int out_size, void* d_ws, size_t ws_size,
                              hipStream_t stream) {
    const float* inputs = (const float*)d_in[0];
    const float* params = (const float*)d_in[1];
    // d_in[2] = mask (unused)
    const float* grid   = (const float*)d_in[3];
    const float* emb_w1 = (const float*)d_in[4];
    const float* emb_b1 = (const float*)d_in[5];
    const float* emb_w2 = (const float*)d_in[6];
    const float* emb_b2 = (const float*)d_in[7];
    const float* mw1 = (const float*)d_in[8];
    const float* mb1 = (const float*)d_in[9];
    const float* mw2 = (const float*)d_in[10];
    const float* mb2 = (const float*)d_in[11];
    const float* uw1 = (const float*)d_in[12];
    const float* ub1 = (const float*)d_in[13];
    const float* uw2 = (const float*)d_in[14];
    const float* ub2 = (const float*)d_in[15];
    const float* ow1 = (const float*)d_in[16];
    const float* ob1 = (const float*)d_in[17];
    const float* ow2 = (const float*)d_in[18];
    const float* ob2 = (const float*)d_in[19];
    float* out = (float*)d_out;

    float* ws  = (float*)d_ws;
    float* pos = ws;                   // BS*NX*2
    float* sq  = pos + BSZ * NXN * 2;  // BS*NX
    float* f   = sq + BSZ * NXN;       // BS*NX*H  (2M floats)
    float* fnew = f + BSZ * NXN * HD;  // BS*NX*H  (2M floats)
    float* mean = fnew + BSZ * NXN * HD;  // BS*H
    float* inv  = mean + BSZ * HD;        // BS*H
    float* p1   = inv + BSZ * HD;         // BS*8*H
    float* p2   = p1 + BSZ * 8 * HD;      // BS*8*H
    float* gmm  = p2 + BSZ * 8 * HD;      // 16
    int* idxw   = (int*)(gmm + 16);       // BS*NX*K ints
    // KNN candidate buffers alias f/fnew: consumed by kknn2 before kembed writes f.
    float* cd = f;       // NJC*KNN * NN floats = 2M floats (exact fit)
    int*   cj = (int*)fnew;

    kminmax<<<BSZ, 256, 0, stream>>>(grid, gmm);
    kpos<<<NN / 256, 256, 0, stream>>>(grid, gmm, pos, sq);
    kknn1<<<BSZ * NJC * (NXN / 256), 256, 0, stream>>>(pos, sq, cd, cj);
    kknn2<<<NN / 256, 256, 0, stream>>>(cd, cj, idxw);
    kembed<<<NN, 128, 0, stream>>>(inputs, pos, params,
                                   emb_w1, emb_b1, emb_w2, emb_b2, f);
    for (int l = 0; l < NLAY; l++) {
        kmsg<<<NN, 128, 0, stream>>>(f, fnew, inputs, pos, params, idxw,
                                     mw1 + l * 264 * HD, mb1 + l * HD,
                                     mw2 + l * HD * HD, mb2 + l * HD,
                                     uw1 + l * 261 * HD, ub1 + l * HD,
                                     uw2 + l * HD * HD, ub2 + l * HD);
        kstats<<<BSZ * 8, 256, 0, stream>>>(fnew, p1, p2);
        kfinal<<<2, 256, 0, stream>>>(p1, p2, mean, inv);
        kapply<<<(BSZ * NXN * HD) / 256, 256, 0, stream>>>(fnew, mean, inv, f);
    }
    khead<<<NN, 64, 0, stream>>>(f, inputs, ow1, ob1, ow2, ob2, out);
}

// Round 3
// 1402.835 us; speedup vs baseline: 3.9213x; 2.5042x over previous
//
#include <hip/hip_runtime.h>
#include <math.h>

#define BSZ 4
#define NXN 4096
#define NPARP 5
#define HD 128
#define NLAY 6
#define KNN 16
#define DTC 0.1f
#define EPSC 1e-5f
#define NJC 8
#define JCH (NXN / NJC)
#define NN (BSZ * NXN)
#define NPB 8          // nodes per block in kmsg2
#define EPB 128        // edges per block

typedef __attribute__((ext_vector_type(8))) short short8;
typedef __attribute__((ext_vector_type(4))) float f32x4;

#define XR(r) (((r) & 7) << 4)

// LDS byte offsets for kmsg2
#define OFF_E   0        // 128 x 256B  (fj bf16 -> h bf16)
#define OFF_AU  32768    // 16 x 512B   (update A: [fi | agg] bf16)
#define OFF_HU  40960    // 16 x 256B   (update hidden bf16)
#define OFF_COM 45056    // 8 x 128 f32
#define OFF_DU  49152    // 128 f32
#define OFF_DPX 49664
#define OFF_DPY 50176
#define OFF_VAR 50688    // [8][8] f32
#define OFF_IDX 50944    // 128 int
#define SMEMB   51456

__device__ __forceinline__ float swishf(float x) {
    return x / (1.0f + __expf(-x));
}

__device__ __forceinline__ unsigned short f2bf(float x) {
    union { float f; unsigned u; } v; v.f = x;
    unsigned r = v.u + 0x7fffu + ((v.u >> 16) & 1u);
    return (unsigned short)(r >> 16);
}

// ---------------- grid min/max per batch ----------------
__global__ void kminmax(const float* __restrict__ grid, float* __restrict__ gmm) {
    int b = blockIdx.x;
    int t = threadIdx.x;
    float mnx = 1e30f, mxx = -1e30f, mny = 1e30f, mxy = -1e30f;
    for (int n = t; n < NXN; n += 256) {
        float x = grid[(b * NXN + n) * 2 + 0];
        float y = grid[(b * NXN + n) * 2 + 1];
        mnx = fminf(mnx, x); mxx = fmaxf(mxx, x);
        mny = fminf(mny, y); mxy = fmaxf(mxy, y);
    }
    __shared__ float s[4][256];
    s[0][t] = mnx; s[1][t] = mxx; s[2][t] = mny; s[3][t] = mxy;
    __syncthreads();
    for (int off = 128; off > 0; off >>= 1) {
        if (t < off) {
            s[0][t] = fminf(s[0][t], s[0][t + off]);
            s[1][t] = fmaxf(s[1][t], s[1][t + off]);
            s[2][t] = fminf(s[2][t], s[2][t + off]);
            s[3][t] = fmaxf(s[3][t], s[3][t + off]);
        }
        __syncthreads();
    }
    if (t == 0) {
        gmm[b * 4 + 0] = s[0][0];
        gmm[b * 4 + 1] = s[1][0];
        gmm[b * 4 + 2] = s[2][0];
        gmm[b * 4 + 3] = s[3][0];
    }
}

// ---------------- pos + sq ----------------
__global__ void kpos(const float* __restrict__ grid, const float* __restrict__ gmm,
                     float* __restrict__ pos, float* __restrict__ sq) {
    int g = blockIdx.x * 256 + threadIdx.x;
    if (g >= NN) return;
    int b = g >> 12;
    float gx = grid[g * 2], gy = grid[g * 2 + 1];
    float px = (gx - gmm[b * 4 + 0]) / (gmm[b * 4 + 1] - gmm[b * 4 + 0]);
    float py = (gy - gmm[b * 4 + 2]) / (gmm[b * 4 + 3] - gmm[b * 4 + 2]);
    pos[g * 2] = px; pos[g * 2 + 1] = py;
    sq[g] = __fadd_rn(__fmul_rn(px, px), __fmul_rn(py, py));
}

// ---------------- KNN phase 1 ----------------
__global__ __launch_bounds__(256) void kknn1(const float* __restrict__ pos,
                                             const float* __restrict__ sq,
                                             float* __restrict__ cd,
                                             int* __restrict__ cj) {
    __shared__ float2 sxy[JCH];
    __shared__ float ss[JCH];
    int blk = blockIdx.x;
    int ib = blk & 15;
    int jc = (blk >> 4) & 7;
    int b  = blk >> 7;
    int t = threadIdx.x;
    for (int n = t; n < JCH; n += 256) {
        int j = jc * JCH + n;
        sxy[n] = *(const float2*)&pos[(b * NXN + j) * 2];
        ss[n] = sq[b * NXN + j];
    }
    __syncthreads();
    int i = ib * 256 + t;
    float2 pi = *(const float2*)&pos[(b * NXN + i) * 2];
    float sqi = sq[b * NXN + i];
    float bd[KNN]; int bj[KNN];
#pragma unroll
    for (int s = 0; s < KNN; s++) { bd[s] = 1e30f; bj[s] = -1; }
    float wd = 1e30f; int wslot = 0;
    int jbase = jc * JCH;
    for (int n = 0; n < JCH; n++) {
        float2 pj = sxy[n];
        float d2 = fmaf(-2.0f, fmaf(pi.x, pj.x, pi.y * pj.y), sqi + ss[n]);
        int j = jbase + n;
        if ((d2 < wd) && (j != i)) {
#pragma unroll
            for (int s = 0; s < KNN; s++) {
                if (s == wslot) { bd[s] = d2; bj[s] = j; }
            }
            wd = bd[0]; wslot = 0;
#pragma unroll
            for (int s = 1; s < KNN; s++) {
                bool w = bd[s] > wd;
                wd = w ? bd[s] : wd;
                wslot = w ? s : wslot;
            }
        }
    }
    int node = b * NXN + i;
#pragma unroll
    for (int s = 0; s < KNN; s++) {
        cd[(jc * KNN + s) * NN + node] = bd[s];
        cj[(jc * KNN + s) * NN + node] = bj[s];
    }
}

// ---------------- KNN phase 2 ----------------
__global__ __launch_bounds__(256) void kknn2(const float* __restrict__ cd,
                                             const int* __restrict__ cj,
                                             int* __restrict__ idxw) {
    int g = blockIdx.x * 256 + threadIdx.x;
    float bd[KNN]; int bj[KNN];
#pragma unroll
    for (int s = 0; s < KNN; s++) { bd[s] = 1e30f; bj[s] = -1; }
    float wd = 1e30f; int wslot = 0;
    for (int c = 0; c < NJC * KNN; c++) {
        float d2 = cd[c * NN + g];
        int j = cj[c * NN + g];
        if (d2 < wd) {
#pragma unroll
            for (int s = 0; s < KNN; s++) {
                if (s == wslot) { bd[s] = d2; bj[s] = j; }
            }
            wd = bd[0]; wslot = 0;
#pragma unroll
            for (int s = 1; s < KNN; s++) {
                bool w = bd[s] > wd;
                wd = w ? bd[s] : wd;
                wslot = w ? s : wslot;
            }
        }
    }
#pragma unroll
    for (int s = 0; s < KNN; s++) idxw[g * KNN + s] = bj[s];
}

// ---------------- weight pack: W[K x 128] f32 -> bf16 [ceil8(K)][128][8] ----------------
__global__ void kpack(const float* __restrict__ src, unsigned short* __restrict__ dst,
                      int K, int KB, int nmat) {
    int g = blockIdx.x * 256 + threadIdx.x;
    int per = KB * 1024;
    if (g >= nmat * per) return;
    int mat = g / per, rem = g % per;
    int kb = rem >> 10, r2 = rem & 1023;
    int n = r2 >> 3, j = r2 & 7;
    int k = kb * 8 + j;
    float v = (k < K) ? src[(mat * K + k) * HD + n] : 0.0f;
    dst[g] = f2bf(v);
}

// ---------------- embedding MLP ----------------
__global__ __launch_bounds__(128) void kembed(const float* __restrict__ inputs,
                                              const float* __restrict__ pos,
                                              const float* __restrict__ params,
                                              const float* __restrict__ w1,
                                              const float* __restrict__ b1,
                                              const float* __restrict__ w2,
                                              const float* __restrict__ b2,
                                              float* __restrict__ f) {
    __shared__ __align__(16) float sh[HD];
    int t = threadIdx.x;
    int g = blockIdx.x;
    float rw1[8];
#pragma unroll
    for (int k = 0; k < 8; k++) rw1[k] = w1[k * HD + t];
    float u = inputs[g];
    float px = pos[g * 2], py = pos[g * 2 + 1];
    float a = b1[t] + u * rw1[0] + px * rw1[1] + py * rw1[2];
#pragma unroll
    for (int j = 0; j < NPARP; j++) a += params[g * NPARP + j] * rw1[3 + j];
    sh[t] = swishf(a);
    __syncthreads();
    float a2 = b2[t];
    for (int k = 0; k < HD; k += 4) {
        float4 s4 = *(const float4*)&sh[k];
        a2 = fmaf(s4.x, w2[(k + 0) * HD + t], a2);
        a2 = fmaf(s4.y, w2[(k + 1) * HD + t], a2);
        a2 = fmaf(s4.z, w2[(k + 2) * HD + t], a2);
        a2 = fmaf(s4.w, w2[(k + 3) * HD + t], a2);
    }
    f[g * HD + t] = swishf(a2);
}

// ---------------- fused MFMA message+aggregate+update, 8 nodes/block ----------------
__global__ __launch_bounds__(256) void kmsg2(
    const float* __restrict__ f, float* __restrict__ fnew,
    const float* __restrict__ inputs, const float* __restrict__ pos,
    const float* __restrict__ params, const int* __restrict__ idxw,
    const unsigned short* __restrict__ W1p, const float* __restrict__ W1r,
    const float* __restrict__ B1,
    const unsigned short* __restrict__ W2p, const float* __restrict__ B2,
    const unsigned short* __restrict__ U1p, const float* __restrict__ U1r,
    const float* __restrict__ UB1,
    const unsigned short* __restrict__ U2p, const float* __restrict__ UB2) {
    __shared__ __align__(16) char sm[SMEMB];
    int tid = threadIdx.x;
    int lane = tid & 63, w = tid >> 6;
    int l15 = lane & 15, l4 = lane >> 4;
    int bn0 = blockIdx.x * NPB;
    int base = bn0 & ~(NXN - 1);

    // ---- stage scalars + fi
    if (tid < EPB) {
        int ni = tid >> 4;
        int gj = idxw[(bn0 + ni) * KNN + (tid & 15)];
        ((int*)(sm + OFF_IDX))[tid] = gj;
        int gn = base + gj;
        ((float*)(sm + OFF_DU))[tid]  = inputs[bn0 + ni] - inputs[gn];
        ((float*)(sm + OFF_DPX))[tid] = pos[(bn0 + ni) * 2]     - pos[gn * 2];
        ((float*)(sm + OFF_DPY))[tid] = pos[(bn0 + ni) * 2 + 1] - pos[gn * 2 + 1];
    } else if (tid < 128 + NPB * NPARP) {
        int t2 = tid - 128;
        ((float*)(sm + OFF_VAR))[(t2 / NPARP) * 8 + (t2 % NPARP)] =
            params[(bn0 + t2 / NPARP) * NPARP + (t2 % NPARP)];
    }
    {   // fi -> sAU rows 0-7 (cols 0..127)
        int r = tid >> 5, c0 = (tid & 31) * 4;
        float4 v = *(const float4*)&f[(bn0 + r) * HD + c0];
        uint2 u2;
        u2.x = f2bf(v.x) | ((unsigned)f2bf(v.y) << 16);
        u2.y = f2bf(v.z) | ((unsigned)f2bf(v.w) << 16);
        *(uint2*)(sm + OFF_AU + r * 512 + ((c0 * 2) ^ XR(r))) = u2;
    }
    {   // zero sAU rows 8-15
        int r = 8 + (tid >> 5), c0 = (tid & 31) * 16;
        uint4 z = {0, 0, 0, 0};
        *(uint4*)(sm + OFF_AU + r * 512 + c0) = z;
    }
    __syncthreads();
    // ---- gather f_j -> sE (bf16, swizzled)
    {
        int r = tid >> 1, hf = tid & 1;
        int gj = ((int*)(sm + OFF_IDX))[r];
        const float* src = &f[(base + gj) * HD + hf * 64];
        char* drow = sm + OFF_E + r * 256;
#pragma unroll
        for (int jj = 0; jj < 8; ++jj) {
            float4 a = ((const float4*)src)[jj * 2];
            float4 b = ((const float4*)src)[jj * 2 + 1];
            uint4 p;
            p.x = f2bf(a.x) | ((unsigned)f2bf(a.y) << 16);
            p.y = f2bf(a.z) | ((unsigned)f2bf(a.w) << 16);
            p.z = f2bf(b.x) | ((unsigned)f2bf(b.y) << 16);
            p.w = f2bf(b.z) | ((unsigned)f2bf(b.w) << 16);
            *(uint4*)(drow + ((hf * 128 + jj * 16) ^ XR(r))) = p;
        }
    }
    __syncthreads();

    // ---- com GEMM: com = B1 + var@W1r[259:] + fi@W1[0:128]   (M=16, 8 valid nodes)
    {
        short8 a[4];
#pragma unroll
        for (int k = 0; k < 4; ++k)
            a[k] = *(short8*)(sm + OFF_AU + l15 * 512 + ((k * 64 + l4 * 16) ^ XR(l15)));
#pragma unroll
        for (int nt2 = 0; nt2 < 2; ++nt2) {
            int nt = w * 2 + nt2;
            int col = nt * 16 + l15;
            float iv0 = B1[col];
            float wv[5];
#pragma unroll
            for (int j = 0; j < 5; ++j) wv[j] = W1r[(259 + j) * HD + col];
            f32x4 acc;
#pragma unroll
            for (int reg = 0; reg < 4; ++reg) {
                int nd = (l4 * 4 + reg) & 7;
                float iv = iv0;
#pragma unroll
                for (int j = 0; j < 5; ++j)
                    iv += ((float*)(sm + OFF_VAR))[nd * 8 + j] * wv[j];
                acc[reg] = iv;
            }
#pragma unroll
            for (int k = 0; k < 4; ++k) {
                short8 bfr = *(const short8*)&W1p[((k * 4 + l4) * HD + col) * 8];
                acc = __builtin_amdgcn_mfma_f32_16x16x32_bf16(a[k], bfr, acc, 0, 0, 0);
            }
#pragma unroll
            for (int reg = 0; reg < 4; ++reg) {
                int nd = l4 * 4 + reg;
                if (nd < 8) ((float*)(sm + OFF_COM))[nd * HD + col] = acc[reg];
            }
        }
    }
    __syncthreads();

    // ---- per-wave preloads
    float wduR[8], wdxR[8], wdyR[8], b2R[8];
#pragma unroll
    for (int nt = 0; nt < 8; ++nt) {
        int col = nt * 16 + l15;
        wduR[nt] = W1r[256 * HD + col];
        wdxR[nt] = W1r[257 * HD + col];
        wdyR[nt] = W1r[258 * HD + col];
        b2R[nt]  = B2[col];
    }

    // ---- edge pipeline (wave-local rows r0..r0+31 = nodes 2w, 2w+1)
    {
        int r0 = w * 32;
        short8 a[2][4];
#pragma unroll
        for (int mt = 0; mt < 2; ++mt)
#pragma unroll
            for (int k = 0; k < 4; ++k) {
                int ra = r0 + mt * 16 + l15;
                a[mt][k] = *(short8*)(sm + OFF_E + ra * 256 + ((k * 64 + l4 * 16) ^ XR(ra)));
            }
        // mm1: h = swish(com + fj@W1[128:256] + du/dpos terms) -> overwrite sE rows
#pragma unroll
        for (int nt = 0; nt < 8; ++nt) {
            int col = nt * 16 + l15;
            short8 bfr[4];
#pragma unroll
            for (int k = 0; k < 4; ++k)
                bfr[k] = *(const short8*)&W1p[(((16 + k * 4) + l4) * HD + col) * 8];
#pragma unroll
            for (int mt = 0; mt < 2; ++mt) {
                int nd = w * 2 + mt;
                float cm = ((float*)(sm + OFF_COM))[nd * HD + col];
                f32x4 acc = {cm, cm, cm, cm};
#pragma unroll
                for (int k = 0; k < 4; ++k)
                    acc = __builtin_amdgcn_mfma_f32_16x16x32_bf16(a[mt][k], bfr[k], acc, 0, 0, 0);
#pragma unroll
                for (int reg = 0; reg < 4; ++reg) {
                    int rr = nd * 16 + l4 * 4 + reg;
                    float hv = acc[reg]
                        + ((float*)(sm + OFF_DU))[rr]  * wduR[nt]
                        + ((float*)(sm + OFF_DPX))[rr] * wdxR[nt]
                        + ((float*)(sm + OFF_DPY))[rr] * wdyR[nt];
                    *(unsigned short*)(sm + OFF_E + rr * 256 + ((col * 2) ^ XR(rr))) =
                        f2bf(swishf(hv));
                }
            }
        }
        // mm2 + mean -> agg into sAU cols 128..255
        short8 h[2][4];
#pragma unroll
        for (int mt = 0; mt < 2; ++mt)
#pragma unroll
            for (int k = 0; k < 4; ++k) {
                int ra = r0 + mt * 16 + l15;
                h[mt][k] = *(short8*)(sm + OFF_E + ra * 256 + ((k * 64 + l4 * 16) ^ XR(ra)));
            }
#pragma unroll
        for (int nt = 0; nt < 8; ++nt) {
            int col = nt * 16 + l15;
            short8 bfr[4];
#pragma unroll
            for (int k = 0; k < 4; ++k)
                bfr[k] = *(const short8*)&W2p[((k * 4 + l4) * HD + col) * 8];
#pragma unroll
            for (int mt = 0; mt < 2; ++mt) {
                int nd = w * 2 + mt;
                f32x4 acc = {b2R[nt], b2R[nt], b2R[nt], b2R[nt]};
#pragma unroll
                for (int k = 0; k < 4; ++k)
                    acc = __builtin_amdgcn_mfma_f32_16x16x32_bf16(h[mt][k], bfr[k], acc, 0, 0, 0);
                float s = swishf(acc[0]) + swishf(acc[1]) + swishf(acc[2]) + swishf(acc[3]);
                s += __shfl_xor(s, 16);
                s += __shfl_xor(s, 32);
                if (lane < 16) {
                    int cb = 256 + (nt * 16 + lane) * 2;
                    *(unsigned short*)(sm + OFF_AU + nd * 512 + (cb ^ XR(nd))) =
                        f2bf(s * 0.0625f);
                }
            }
        }
    }
    __syncthreads();

    // ---- update MLP stage 1: K=256 ([fi|agg]) -> swish -> sHU
    {
        short8 au[8];
#pragma unroll
        for (int k = 0; k < 8; ++k)
            au[k] = *(short8*)(sm + OFF_AU + l15 * 512 + ((k * 64 + l4 * 16) ^ XR(l15)));
#pragma unroll
        for (int nt2 = 0; nt2 < 2; ++nt2) {
            int nt = w * 2 + nt2;
            int col = nt * 16 + l15;
            float iv0 = UB1[col];
            float wv[5];
#pragma unroll
            for (int j = 0; j < 5; ++j) wv[j] = U1r[(256 + j) * HD + col];
            f32x4 acc;
#pragma unroll
            for (int reg = 0; reg < 4; ++reg) {
                int nd = (l4 * 4 + reg) & 7;
                float iv = iv0;
#pragma unroll
                for (int j = 0; j < 5; ++j)
                    iv += ((float*)(sm + OFF_VAR))[nd * 8 + j] * wv[j];
                acc[reg] = iv;
            }
#pragma unroll
            for (int k = 0; k < 8; ++k) {
                short8 bfr = *(const short8*)&U1p[((k * 4 + l4) * HD + col) * 8];
                acc = __builtin_amdgcn_mfma_f32_16x16x32_bf16(au[k], bfr, acc, 0, 0, 0);
            }
#pragma unroll
            for (int reg = 0; reg < 4; ++reg) {
                int row = l4 * 4 + reg;
                *(unsigned short*)(sm + OFF_HU + row * 256 + ((col * 2) ^ XR(row))) =
                    f2bf(swishf(acc[reg]));
            }
        }
    }
    __syncthreads();
    // ---- update MLP stage 2: K=128 -> residual -> fnew
    {
        short8 ah[4];
#pragma unroll
        for (int k = 0; k < 4; ++k)
            ah[k] = *(short8*)(sm + OFF_HU + l15 * 256 + ((k * 64 + l4 * 16) ^ XR(l15)));
#pragma unroll
        for (int nt2 = 0; nt2 < 2; ++nt2) {
            int nt = w * 2 + nt2;
            int col = nt * 16 + l15;
            float ub = UB2[col];
            f32x4 acc = {ub, ub, ub, ub};
#pragma unroll
            for (int k = 0; k < 4; ++k) {
                short8 bfr = *(const short8*)&U2p[((k * 4 + l4) * HD + col) * 8];
                acc = __builtin_amdgcn_mfma_f32_16x16x32_bf16(ah[k], bfr, acc, 0, 0, 0);
            }
#pragma unroll
            for (int reg = 0; reg < 4; ++reg) {
                int nd = l4 * 4 + reg;
                if (nd < 8) {
                    int gi = (bn0 + nd) * HD + col;
                    fnew[gi] = f[gi] + swishf(acc[reg]);
                }
            }
        }
    }
}

// ---------------- instance norm: stats, finalize, apply ----------------
__global__ __launch_bounds__(256) void kstats(const float* __restrict__ fnew,
                                              float* __restrict__ p1, float* __restrict__ p2) {
    int blk = blockIdx.x;
    int b = blk >> 3;
    int ch = blk & 7;
    int t = threadIdx.x;
    int c = t & 127;
    int half = t >> 7;
    int nbase = ch * 512;
    float s1 = 0.0f, s2 = 0.0f;
    for (int n = half; n < 512; n += 2) {
        float v = fnew[((b * NXN) + (nbase + n)) * HD + c];
        s1 += v; s2 += v * v;
    }
    __shared__ float r1[256], r2[256];
    r1[t] = s1; r2[t] = s2;
    __syncthreads();
    if (half == 0) {
        s1 += r1[t + 128]; s2 += r2[t + 128];
        p1[blk * HD + c] = s1;
        p2[blk * HD + c] = s2;
    }
}

__global__ void kfinal(const float* __restrict__ p1, const float* __restrict__ p2,
                       float* __restrict__ mean, float* __restrict__ inv) {
    int g = blockIdx.x * 256 + threadIdx.x;
    if (g >= BSZ * HD) return;
    int b = g >> 7;
    int c = g & 127;
    float s1 = 0.0f, s2 = 0.0f;
#pragma unroll
    for (int ch = 0; ch < 8; ch++) {
        s1 += p1[(b * 8 + ch) * HD + c];
        s2 += p2[(b * 8 + ch) * HD + c];
    }
    float m = s1 * (1.0f / NXN);
    float v = s2 * (1.0f / NXN) - m * m;
    mean[g] = m;
    inv[g] = rsqrtf(v + EPSC);
}

__global__ void kapply(const float* __restrict__ fnew, const float* __restrict__ mean,
                       const float* __restrict__ inv, float* __restrict__ f) {
    int g = blockIdx.x * 256 + threadIdx.x;
    int b = g >> 19;
    int c = g & 127;
    f[g] = (fnew[g] - mean[b * HD + c]) * inv[b * HD + c];
}

// ---------------- output head ----------------
__global__ __launch_bounds__(64) void khead(const float* __restrict__ f,
                                            const float* __restrict__ inputs,
                                            const float* __restrict__ ow1,
                                            const float* __restrict__ ob1,
                                            const float* __restrict__ ow2,
                                            const float* __restrict__ ob2,
                                            float* __restrict__ out) {
    int bn = blockIdx.x;
    int c = threadIdx.x;
    float a = ob1[c];
    for (int k = 0; k < HD; k++) a += f[bn * HD + k] * ow1[k * 64 + c];
    float v = swishf(a) * ow2[c];
#pragma unroll
    for (int off = 32; off > 0; off >>= 1) v += __shfl_down(v, off);
    if (c == 0) out[bn] = inputs[bn] + DTC * (v + ob2[0]);
}

extern "C" void kernel_launch(void* const* d_in, const int* in_sizes, int n_in,
                              void* d_out, int out_size, void* d_ws, size_t ws_size,
                              hipStream_t stream) {
    const float* inputs = (const float*)d_in[0];
    const float* params = (const float*)d_in[1];
    const float* grid   = (const float*)d_in[3];
    const float* emb_w1 = (const float*)d_in[4];
    const float* emb_b1 = (const float*)d_in[5];
    const float* emb_w2 = (const float*)d_in[6];
    const float* emb_b2 = (const float*)d_in[7];
    const float* mw1 = (const float*)d_in[8];
    const float* mb1 = (const float*)d_in[9];
    const float* mw2 = (const float*)d_in[10];
    const float* mb2 = (const float*)d_in[11];
    const float* uw1 = (const float*)d_in[12];
    const float* ub1 = (const float*)d_in[13];
    const float* uw2 = (const float*)d_in[14];
    const float* ub2 = (const float*)d_in[15];
    const float* ow1 = (const float*)d_in[16];
    const float* ob1 = (const float*)d_in[17];
    const float* ow2 = (const float*)d_in[18];
    const float* ob2 = (const float*)d_in[19];
    float* out = (float*)d_out;

    float* ws  = (float*)d_ws;
    float* pos = ws;                      // BS*NX*2
    float* sq  = pos + BSZ * NXN * 2;     // BS*NX
    float* f   = sq + BSZ * NXN;          // BS*NX*H
    float* fnew = f + BSZ * NXN * HD;     // BS*NX*H
    float* mean = fnew + BSZ * NXN * HD;  // BS*H
    float* inv  = mean + BSZ * HD;        // BS*H
    float* p1   = inv + BSZ * HD;         // BS*8*H
    float* p2   = p1 + BSZ * 8 * HD;      // BS*8*H
    float* gmm  = p2 + BSZ * 8 * HD;      // 16
    int* idxw   = (int*)(gmm + 16);       // BS*NX*K ints
    unsigned short* mw1p = (unsigned short*)(idxw + NN * KNN);  // 6*33*1024
    unsigned short* mw2p = mw1p + 6 * 33 * 1024;                // 6*16*1024
    unsigned short* uw1p = mw2p + 6 * 16 * 1024;                // 6*33*1024
    unsigned short* uw2p = uw1p + 6 * 33 * 1024;                // 6*16*1024
    // KNN candidate buffers alias f/fnew (consumed before kembed writes f)
    float* cd = f;
    int*   cj = (int*)fnew;

    kminmax<<<BSZ, 256, 0, stream>>>(grid, gmm);
    kpos<<<NN / 256, 256, 0, stream>>>(grid, gmm, pos, sq);
    kknn1<<<BSZ * NJC * (NXN / 256), 256, 0, stream>>>(pos, sq, cd, cj);
    kknn2<<<NN / 256, 256, 0, stream>>>(cd, cj, idxw);

    kpack<<<(6 * 33 * 1024 + 255) / 256, 256, 0, stream>>>(mw1, mw1p, 264, 33, 6);
    kpack<<<(6 * 16 * 1024 + 255) / 256, 256, 0, stream>>>(mw2, mw2p, 128, 16, 6);
    kpack<<<(6 * 33 * 1024 + 255) / 256, 256, 0, stream>>>(uw1, uw1p, 261, 33, 6);
    kpack<<<(6 * 16 * 1024 + 255) / 256, 256, 0, stream>>>(uw2, uw2p, 128, 16, 6);

    kembed<<<NN, 128, 0, stream>>>(inputs, pos, params,
                                   emb_w1, emb_b1, emb_w2, emb_b2, f);
    for (int l = 0; l < NLAY; l++) {
        kmsg2<<<NN / NPB, 256, 0, stream>>>(f, fnew, inputs, pos, params, idxw,
                                            mw1p + l * 33 * 1024, mw1 + l * 264 * HD, mb1 + l * HD,
                                            mw2p + l * 16 * 1024, mb2 + l * HD,
                                            uw1p + l * 33 * 1024, uw1 + l * 261 * HD, ub1 + l * HD,
                                            uw2p + l * 16 * 1024, ub2 + l * HD);
        kstats<<<BSZ * 8, 256, 0, stream>>>(fnew, p1, p2);
        kfinal<<<2, 256, 0, stream>>>(p1, p2, mean, inv);
        kapply<<<(BSZ * NXN * HD) / 256, 256, 0, stream>>>(fnew, mean, inv, f);
    }
    khead<<<NN, 64, 0, stream>>>(f, inputs, ow1, ob1, ow2, ob2, out);
}

// Round 4
// 1119.206 us; speedup vs baseline: 4.9150x; 1.2534x over previous
//
#include <hip/hip_runtime.h>
#include <math.h>

#define BSZ 4
#define NXN 4096
#define NPARP 5
#define HD 128
#define NLAY 6
#define KNN 16
#define DTC 0.1f
#define EPSC 1e-5f
#define NN (BSZ * NXN)
#define NPB 8          // nodes per block in kmsg2
#define EPB 128        // edges per block

typedef __attribute__((ext_vector_type(8))) short short8;
typedef __attribute__((ext_vector_type(4))) float f32x4;

#define XR(r) (((r) & 7) << 4)

// LDS byte offsets for kmsg2
#define OFF_E   0        // 128 x 256B  (fj bf16 -> h bf16)
#define OFF_AU  32768    // 16 x 512B   (update A: [fi | agg] bf16)
#define OFF_HU  40960    // 16 x 256B   (update hidden bf16)
#define OFF_COM 45056    // 8 x 128 f32
#define OFF_DU  49152    // 128 f32
#define OFF_DPX 49664
#define OFF_DPY 50176
#define OFF_VAR 50688    // [8][8] f32
#define OFF_IDX 50944    // 128 int
#define SMEMB   51456

__device__ __forceinline__ float swishf(float x) {
    return x / (1.0f + __expf(-x));
}

// round-to-nearest bf16 (weights only)
__device__ __forceinline__ unsigned short f2bf(float x) {
    union { float f; unsigned u; } v; v.f = x;
    unsigned r = v.u + 0x7fffu + ((v.u >> 16) & 1u);
    return (unsigned short)(r >> 16);
}
// truncation bf16 (activations; 1 VALU op)
__device__ __forceinline__ unsigned short trh(float x) {
    union { float f; unsigned u; } v; v.f = x;
    return (unsigned short)(v.u >> 16);
}
__device__ __forceinline__ unsigned trpk(float lo, float hi) {
    union { float f; unsigned u; } a, b; a.f = lo; b.f = hi;
    return (b.u & 0xFFFF0000u) | (a.u >> 16);
}

// ---------------- grid min/max per batch ----------------
__global__ void kminmax(const float* __restrict__ grid, float* __restrict__ gmm) {
    int b = blockIdx.x;
    int t = threadIdx.x;
    float mnx = 1e30f, mxx = -1e30f, mny = 1e30f, mxy = -1e30f;
    for (int n = t; n < NXN; n += 256) {
        float x = grid[(b * NXN + n) * 2 + 0];
        float y = grid[(b * NXN + n) * 2 + 1];
        mnx = fminf(mnx, x); mxx = fmaxf(mxx, x);
        mny = fminf(mny, y); mxy = fmaxf(mxy, y);
    }
    __shared__ float s[4][256];
    s[0][t] = mnx; s[1][t] = mxx; s[2][t] = mny; s[3][t] = mxy;
    __syncthreads();
    for (int off = 128; off > 0; off >>= 1) {
        if (t < off) {
            s[0][t] = fminf(s[0][t], s[0][t + off]);
            s[1][t] = fmaxf(s[1][t], s[1][t + off]);
            s[2][t] = fminf(s[2][t], s[2][t + off]);
            s[3][t] = fmaxf(s[3][t], s[3][t + off]);
        }
        __syncthreads();
    }
    if (t == 0) {
        gmm[b * 4 + 0] = s[0][0];
        gmm[b * 4 + 1] = s[1][0];
        gmm[b * 4 + 2] = s[2][0];
        gmm[b * 4 + 3] = s[3][0];
    }
}

// ---------------- pos + sq ----------------
__global__ void kpos(const float* __restrict__ grid, const float* __restrict__ gmm,
                     float* __restrict__ pos, float* __restrict__ sq) {
    int g = blockIdx.x * 256 + threadIdx.x;
    if (g >= NN) return;
    int b = g >> 12;
    float gx = grid[g * 2], gy = grid[g * 2 + 1];
    float px = (gx - gmm[b * 4 + 0]) / (gmm[b * 4 + 1] - gmm[b * 4 + 0]);
    float py = (gy - gmm[b * 4 + 2]) / (gmm[b * 4 + 3] - gmm[b * 4 + 2]);
    pos[g * 2] = px; pos[g * 2 + 1] = py;
    sq[g] = __fadd_rn(__fmul_rn(px, px), __fmul_rn(py, py));
}

// ---------------- KNN: one wave per node, 16 extraction rounds ----------------
// lane L owns candidates j = t*64 + L (t=0..63) held exactly in registers.
__global__ __launch_bounds__(256) void kknnW(const float* __restrict__ pos,
                                             const float* __restrict__ sq,
                                             int* __restrict__ idxw) {
    __shared__ float2 sxy[NXN];
    __shared__ float ssq[NXN];
    int blk = blockIdx.x;           // 512 blocks: b = blk>>7
    int b = blk >> 7;
    int t = threadIdx.x;
    int lane = t & 63, w = t >> 6;
    for (int n = t; n < NXN; n += 256) {
        sxy[n] = *(const float2*)&pos[(b * NXN + n) * 2];
        ssq[n] = sq[b * NXN + n];
    }
    __syncthreads();
    int i0 = (blk & 127) * 32 + w * 8;
    for (int it = 0; it < 8; ++it) {
        int i = i0 + it;
        float2 pi = sxy[i];
        float sqi = ssq[i];
        int tself = (lane == (i & 63)) ? (i >> 6) : 64;
        float pk[64];
        float g0 = 1e38f, g1 = 1e38f, g2 = 1e38f, g3 = 1e38f;
#pragma unroll
        for (int tt = 0; tt < 64; ++tt) {
            int j = tt * 64 + lane;
            float2 pj = sxy[j];
            float dot = fmaf(pi.x, pj.x, pi.y * pj.y);
            float d2 = (sqi + ssq[j]) - 2.0f * dot;
            d2 = (tt == tself) ? 1e38f : d2;
            pk[tt] = d2;
            if (tt < 16) g0 = fminf(g0, d2);
            else if (tt < 32) g1 = fminf(g1, d2);
            else if (tt < 48) g2 = fminf(g2, d2);
            else g3 = fminf(g3, d2);
        }
        int obase = (b * NXN + i) * KNN;
#pragma unroll 1
        for (int r = 0; r < KNN; ++r) {
            float m = fminf(fminf(g0, g1), fminf(g2, g3));
            float gm = m;
#pragma unroll
            for (int off = 1; off < 64; off <<= 1)
                gm = fminf(gm, __shfl_xor(gm, off));
            if (m == gm) {           // winner lane(s) only
                int jt = 0;
                if (g0 == gm) {
                    float ng = 1e38f;
#pragma unroll
                    for (int tt = 0; tt < 16; ++tt) {
                        bool hit = (pk[tt] == gm);
                        jt = hit ? tt : jt;
                        pk[tt] = hit ? 1e38f : pk[tt];
                        ng = fminf(ng, pk[tt]);
                    }
                    g0 = ng;
                }
                if (g1 == gm) {
                    float ng = 1e38f;
#pragma unroll
                    for (int tt = 16; tt < 32; ++tt) {
                        bool hit = (pk[tt] == gm);
                        jt = hit ? tt : jt;
                        pk[tt] = hit ? 1e38f : pk[tt];
                        ng = fminf(ng, pk[tt]);
                    }
                    g1 = ng;
                }
                if (g2 == gm) {
                    float ng = 1e38f;
#pragma unroll
                    for (int tt = 32; tt < 48; ++tt) {
                        bool hit = (pk[tt] == gm);
                        jt = hit ? tt : jt;
                        pk[tt] = hit ? 1e38f : pk[tt];
                        ng = fminf(ng, pk[tt]);
                    }
                    g2 = ng;
                }
                if (g3 == gm) {
                    float ng = 1e38f;
#pragma unroll
                    for (int tt = 48; tt < 64; ++tt) {
                        bool hit = (pk[tt] == gm);
                        jt = hit ? tt : jt;
                        pk[tt] = hit ? 1e38f : pk[tt];
                        ng = fminf(ng, pk[tt]);
                    }
                    g3 = ng;
                }
                idxw[obase + r] = jt * 64 + lane;
            }
        }
    }
}

// ---------------- weight pack: W[K x 128] f32 -> bf16 [ceil8(K)][128][8] ----------------
__global__ void kpack(const float* __restrict__ src, unsigned short* __restrict__ dst,
                      int K, int KB, int nmat) {
    int g = blockIdx.x * 256 + threadIdx.x;
    int per = KB * 1024;
    if (g >= nmat * per) return;
    int mat = g / per, rem = g % per;
    int kb = rem >> 10, r2 = rem & 1023;
    int n = r2 >> 3, j = r2 & 7;
    int k = kb * 8 + j;
    float v = (k < K) ? src[(mat * K + k) * HD + n] : 0.0f;
    dst[g] = f2bf(v);
}

// ---------------- embedding MLP ----------------
__global__ __launch_bounds__(128) void kembed(const float* __restrict__ inputs,
                                              const float* __restrict__ pos,
                                              const float* __restrict__ params,
                                              const float* __restrict__ w1,
                                              const float* __restrict__ b1,
                                              const float* __restrict__ w2,
                                              const float* __restrict__ b2,
                                              float* __restrict__ f) {
    __shared__ __align__(16) float sh[HD];
    int t = threadIdx.x;
    int g = blockIdx.x;
    float rw1[8];
#pragma unroll
    for (int k = 0; k < 8; k++) rw1[k] = w1[k * HD + t];
    float u = inputs[g];
    float px = pos[g * 2], py = pos[g * 2 + 1];
    float a = b1[t] + u * rw1[0] + px * rw1[1] + py * rw1[2];
#pragma unroll
    for (int j = 0; j < NPARP; j++) a += params[g * NPARP + j] * rw1[3 + j];
    sh[t] = swishf(a);
    __syncthreads();
    float a2 = b2[t];
    for (int k = 0; k < HD; k += 4) {
        float4 s4 = *(const float4*)&sh[k];
        a2 = fmaf(s4.x, w2[(k + 0) * HD + t], a2);
        a2 = fmaf(s4.y, w2[(k + 1) * HD + t], a2);
        a2 = fmaf(s4.z, w2[(k + 2) * HD + t], a2);
        a2 = fmaf(s4.w, w2[(k + 3) * HD + t], a2);
    }
    f[g * HD + t] = swishf(a2);
}

// ---------------- fused MFMA message+aggregate+update, 8 nodes/block ----------------
__global__ __launch_bounds__(256) void kmsg2(
    const float* __restrict__ f, float* __restrict__ fnew,
    const float* __restrict__ inputs, const float* __restrict__ pos,
    const float* __restrict__ params, const int* __restrict__ idxw,
    const unsigned short* __restrict__ W1p, const float* __restrict__ W1r,
    const float* __restrict__ B1,
    const unsigned short* __restrict__ W2p, const float* __restrict__ B2,
    const unsigned short* __restrict__ U1p, const float* __restrict__ U1r,
    const float* __restrict__ UB1,
    const unsigned short* __restrict__ U2p, const float* __restrict__ UB2) {
    __shared__ __align__(16) char sm[SMEMB];
    int tid = threadIdx.x;
    int lane = tid & 63, w = tid >> 6;
    int l15 = lane & 15, l4 = lane >> 4;
    int bn0 = blockIdx.x * NPB;
    int base = bn0 & ~(NXN - 1);

    // ---- stage scalars + fi
    if (tid < EPB) {
        int ni = tid >> 4;
        int gj = idxw[(bn0 + ni) * KNN + (tid & 15)];
        ((int*)(sm + OFF_IDX))[tid] = gj;
        int gn = base + gj;
        ((float*)(sm + OFF_DU))[tid]  = inputs[bn0 + ni] - inputs[gn];
        ((float*)(sm + OFF_DPX))[tid] = pos[(bn0 + ni) * 2]     - pos[gn * 2];
        ((float*)(sm + OFF_DPY))[tid] = pos[(bn0 + ni) * 2 + 1] - pos[gn * 2 + 1];
    } else if (tid < 128 + NPB * NPARP) {
        int t2 = tid - 128;
        ((float*)(sm + OFF_VAR))[(t2 / NPARP) * 8 + (t2 % NPARP)] =
            params[(bn0 + t2 / NPARP) * NPARP + (t2 % NPARP)];
    }
    {   // fi -> sAU rows 0-7 (cols 0..127)
        int r = tid >> 5, c0 = (tid & 31) * 4;
        float4 v = *(const float4*)&f[(bn0 + r) * HD + c0];
        uint2 u2;
        u2.x = trpk(v.x, v.y);
        u2.y = trpk(v.z, v.w);
        *(uint2*)(sm + OFF_AU + r * 512 + ((c0 * 2) ^ XR(r))) = u2;
    }
    {   // zero sAU rows 8-15
        int r = 8 + (tid >> 5), c0 = (tid & 31) * 16;
        uint4 z = {0, 0, 0, 0};
        *(uint4*)(sm + OFF_AU + r * 512 + c0) = z;
    }
    __syncthreads();
    // ---- gather f_j -> sE (bf16 trunc, swizzled)
    {
        int r = tid >> 1, hf = tid & 1;
        int gj = ((int*)(sm + OFF_IDX))[r];
        const float* src = &f[(base + gj) * HD + hf * 64];
        char* drow = sm + OFF_E + r * 256;
#pragma unroll
        for (int jj = 0; jj < 8; ++jj) {
            float4 a = ((const float4*)src)[jj * 2];
            float4 bq = ((const float4*)src)[jj * 2 + 1];
            uint4 p;
            p.x = trpk(a.x, a.y);
            p.y = trpk(a.z, a.w);
            p.z = trpk(bq.x, bq.y);
            p.w = trpk(bq.z, bq.w);
            *(uint4*)(drow + ((hf * 128 + jj * 16) ^ XR(r))) = p;
        }
    }
    __syncthreads();

    // ---- com GEMM: com = B1 + var@W1r[259:] + fi@W1[0:128]   (M=16, 8 valid nodes)
    {
        short8 a[4];
#pragma unroll
        for (int k = 0; k < 4; ++k)
            a[k] = *(short8*)(sm + OFF_AU + l15 * 512 + ((k * 64 + l4 * 16) ^ XR(l15)));
        // preload both col-tiles' B-fragments up front (hide L2 latency)
        short8 bc0[4], bc1[4];
        int col0 = (w * 2) * 16 + l15, col1 = (w * 2 + 1) * 16 + l15;
#pragma unroll
        for (int k = 0; k < 4; ++k) {
            bc0[k] = *(const short8*)&W1p[((k * 4 + l4) * HD + col0) * 8];
            bc1[k] = *(const short8*)&W1p[((k * 4 + l4) * HD + col1) * 8];
        }
#pragma unroll
        for (int nt2 = 0; nt2 < 2; ++nt2) {
            int col = nt2 ? col1 : col0;
            float iv0 = B1[col];
            float wv[5];
#pragma unroll
            for (int j = 0; j < 5; ++j) wv[j] = W1r[(259 + j) * HD + col];
            f32x4 acc;
#pragma unroll
            for (int reg = 0; reg < 4; ++reg) {
                int nd = (l4 * 4 + reg) & 7;
                float iv = iv0;
#pragma unroll
                for (int j = 0; j < 5; ++j)
                    iv += ((float*)(sm + OFF_VAR))[nd * 8 + j] * wv[j];
                acc[reg] = iv;
            }
#pragma unroll
            for (int k = 0; k < 4; ++k)
                acc = __builtin_amdgcn_mfma_f32_16x16x32_bf16(a[k], nt2 ? bc1[k] : bc0[k], acc, 0, 0, 0);
#pragma unroll
            for (int reg = 0; reg < 4; ++reg) {
                int nd = l4 * 4 + reg;
                if (nd < 8) ((float*)(sm + OFF_COM))[nd * HD + col] = acc[reg];
            }
        }
    }
    __syncthreads();

    // ---- hoisted du/dpos for this wave's rows
    float duR[2][4], dpxR[2][4], dpyR[2][4];
#pragma unroll
    for (int mt = 0; mt < 2; ++mt)
#pragma unroll
        for (int reg = 0; reg < 4; ++reg) {
            int rr = (w * 2 + mt) * 16 + l4 * 4 + reg;
            duR[mt][reg]  = ((float*)(sm + OFF_DU))[rr];
            dpxR[mt][reg] = ((float*)(sm + OFF_DPX))[rr];
            dpyR[mt][reg] = ((float*)(sm + OFF_DPY))[rr];
        }

    // ---- edge pipeline (wave-local rows r0..r0+31 = nodes 2w, 2w+1)
    {
        int r0 = w * 32;
        short8 a[2][4];
#pragma unroll
        for (int mt = 0; mt < 2; ++mt)
#pragma unroll
            for (int k = 0; k < 4; ++k) {
                int ra = r0 + mt * 16 + l15;
                a[mt][k] = *(short8*)(sm + OFF_E + ra * 256 + ((k * 64 + l4 * 16) ^ XR(ra)));
            }
        // mm1 with prefetch-1 on weight fragments
        short8 bc[4];
        float wdu, wdx, wdy;
        {
            int col = l15;
#pragma unroll
            for (int k = 0; k < 4; ++k)
                bc[k] = *(const short8*)&W1p[(((16 + k * 4) + l4) * HD + col) * 8];
            wdu = W1r[256 * HD + col];
            wdx = W1r[257 * HD + col];
            wdy = W1r[258 * HD + col];
        }
#pragma unroll 1
        for (int nt = 0; nt < 8; ++nt) {
            int col = nt * 16 + l15;
            int ncol = (nt < 7) ? col + 16 : col;
            short8 bn_[4];
#pragma unroll
            for (int k = 0; k < 4; ++k)
                bn_[k] = *(const short8*)&W1p[(((16 + k * 4) + l4) * HD + ncol) * 8];
            float wduN = W1r[256 * HD + ncol];
            float wdxN = W1r[257 * HD + ncol];
            float wdyN = W1r[258 * HD + ncol];
#pragma unroll
            for (int mt = 0; mt < 2; ++mt) {
                int nd = w * 2 + mt;
                float cm = ((float*)(sm + OFF_COM))[nd * HD + col];
                f32x4 acc = {cm, cm, cm, cm};
#pragma unroll
                for (int k = 0; k < 4; ++k)
                    acc = __builtin_amdgcn_mfma_f32_16x16x32_bf16(a[mt][k], bc[k], acc, 0, 0, 0);
#pragma unroll
                for (int reg = 0; reg < 4; ++reg) {
                    int rr = nd * 16 + l4 * 4 + reg;
                    float hv = acc[reg]
                        + duR[mt][reg]  * wdu
                        + dpxR[mt][reg] * wdx
                        + dpyR[mt][reg] * wdy;
                    *(unsigned short*)(sm + OFF_E + rr * 256 + ((col * 2) ^ XR(rr))) =
                        trh(swishf(hv));
                }
            }
#pragma unroll
            for (int k = 0; k < 4; ++k) bc[k] = bn_[k];
            wdu = wduN; wdx = wdxN; wdy = wdyN;
        }
        // mm2 + mean -> agg into sAU cols 128..255 (prefetch-1)
        short8 h[2][4];
#pragma unroll
        for (int mt = 0; mt < 2; ++mt)
#pragma unroll
            for (int k = 0; k < 4; ++k) {
                int ra = r0 + mt * 16 + l15;
                h[mt][k] = *(short8*)(sm + OFF_E + ra * 256 + ((k * 64 + l4 * 16) ^ XR(ra)));
            }
        short8 c2[4];
        float b2c;
        {
            int col = l15;
#pragma unroll
            for (int k = 0; k < 4; ++k)
                c2[k] = *(const short8*)&W2p[((k * 4 + l4) * HD + col) * 8];
            b2c = B2[col];
        }
#pragma unroll 1
        for (int nt = 0; nt < 8; ++nt) {
            int col = nt * 16 + l15;
            int ncol = (nt < 7) ? col + 16 : col;
            short8 nx[4];
#pragma unroll
            for (int k = 0; k < 4; ++k)
                nx[k] = *(const short8*)&W2p[((k * 4 + l4) * HD + ncol) * 8];
            float b2N = B2[ncol];
#pragma unroll
            for (int mt = 0; mt < 2; ++mt) {
                int nd = w * 2 + mt;
                f32x4 acc = {b2c, b2c, b2c, b2c};
#pragma unroll
                for (int k = 0; k < 4; ++k)
                    acc = __builtin_amdgcn_mfma_f32_16x16x32_bf16(h[mt][k], c2[k], acc, 0, 0, 0);
                float s = swishf(acc[0]) + swishf(acc[1]) + swishf(acc[2]) + swishf(acc[3]);
                s += __shfl_xor(s, 16);
                s += __shfl_xor(s, 32);
                if (lane < 16) {
                    int cb = 256 + (nt * 16 + lane) * 2;
                    *(unsigned short*)(sm + OFF_AU + nd * 512 + (cb ^ XR(nd))) =
                        trh(s * 0.0625f);
                }
            }
#pragma unroll
            for (int k = 0; k < 4; ++k) c2[k] = nx[k];
            b2c = b2N;
        }
    }
    __syncthreads();

    // ---- update MLP stage 1: K=256 ([fi|agg]) -> swish -> sHU
    {
        short8 au[8];
#pragma unroll
        for (int k = 0; k < 8; ++k)
            au[k] = *(short8*)(sm + OFF_AU + l15 * 512 + ((k * 64 + l4 * 16) ^ XR(l15)));
#pragma unroll
        for (int nt2 = 0; nt2 < 2; ++nt2) {
            int nt = w * 2 + nt2;
            int col = nt * 16 + l15;
            float iv0 = UB1[col];
            float wv[5];
#pragma unroll
            for (int j = 0; j < 5; ++j) wv[j] = U1r[(256 + j) * HD + col];
            f32x4 acc;
#pragma unroll
            for (int reg = 0; reg < 4; ++reg) {
                int nd = (l4 * 4 + reg) & 7;
                float iv = iv0;
#pragma unroll
                for (int j = 0; j < 5; ++j)
                    iv += ((float*)(sm + OFF_VAR))[nd * 8 + j] * wv[j];
                acc[reg] = iv;
            }
#pragma unroll
            for (int k = 0; k < 8; ++k) {
                short8 bfr = *(const short8*)&U1p[((k * 4 + l4) * HD + col) * 8];
                acc = __builtin_amdgcn_mfma_f32_16x16x32_bf16(au[k], bfr, acc, 0, 0, 0);
            }
#pragma unroll
            for (int reg = 0; reg < 4; ++reg) {
                int row = l4 * 4 + reg;
                *(unsigned short*)(sm + OFF_HU + row * 256 + ((col * 2) ^ XR(row))) =
                    trh(swishf(acc[reg]));
            }
        }
    }
    __syncthreads();
    // ---- update MLP stage 2: K=128 -> residual -> fnew  (preload both col-tiles)
    {
        short8 ah[4];
#pragma unroll
        for (int k = 0; k < 4; ++k)
            ah[k] = *(short8*)(sm + OFF_HU + l15 * 256 + ((k * 64 + l4 * 16) ^ XR(l15)));
        short8 bc0[4], bc1[4];
        int col0 = (w * 2) * 16 + l15, col1 = (w * 2 + 1) * 16 + l15;
#pragma unroll
        for (int k = 0; k < 4; ++k) {
            bc0[k] = *(const short8*)&U2p[((k * 4 + l4) * HD + col0) * 8];
            bc1[k] = *(const short8*)&U2p[((k * 4 + l4) * HD + col1) * 8];
        }
#pragma unroll
        for (int nt2 = 0; nt2 < 2; ++nt2) {
            int col = nt2 ? col1 : col0;
            float ub = UB2[col];
            f32x4 acc = {ub, ub, ub, ub};
#pragma unroll
            for (int k = 0; k < 4; ++k)
                acc = __builtin_amdgcn_mfma_f32_16x16x32_bf16(ah[k], nt2 ? bc1[k] : bc0[k], acc, 0, 0, 0);
#pragma unroll
            for (int reg = 0; reg < 4; ++reg) {
                int nd = l4 * 4 + reg;
                if (nd < 8) {
                    int gi = (bn0 + nd) * HD + col;
                    fnew[gi] = f[gi] + swishf(acc[reg]);
                }
            }
        }
    }
}

// ---------------- instance norm: stats (partial) + fused finalize/apply ----------------
__global__ __launch_bounds__(256) void kstats(const float* __restrict__ fnew,
                                              float* __restrict__ p1, float* __restrict__ p2) {
    int blk = blockIdx.x;
    int b = blk >> 3;
    int ch = blk & 7;
    int t = threadIdx.x;
    int c = t & 127;
    int half = t >> 7;
    int nbase = ch * 512;
    float s1 = 0.0f, s2 = 0.0f;
    for (int n = half; n < 512; n += 2) {
        float v = fnew[((b * NXN) + (nbase + n)) * HD + c];
        s1 += v; s2 += v * v;
    }
    __shared__ float r1[256], r2[256];
    r1[t] = s1; r2[t] = s2;
    __syncthreads();
    if (half == 0) {
        s1 += r1[t + 128]; s2 += r2[t + 128];
        p1[blk * HD + c] = s1;
        p2[blk * HD + c] = s2;
    }
}

__global__ void kapply2(const float* __restrict__ fnew,
                        const float* __restrict__ p1, const float* __restrict__ p2,
                        float* __restrict__ f) {
    int g = blockIdx.x * 256 + threadIdx.x;
    int b = g >> 19;
    int c = g & 127;
    float s1 = 0.0f, s2 = 0.0f;
#pragma unroll
    for (int ch = 0; ch < 8; ch++) {
        s1 += p1[(b * 8 + ch) * HD + c];
        s2 += p2[(b * 8 + ch) * HD + c];
    }
    float m = s1 * (1.0f / NXN);
    float v = s2 * (1.0f / NXN) - m * m;
    f[g] = (fnew[g] - m) * rsqrtf(v + EPSC);
}

// ---------------- output head ----------------
__global__ __launch_bounds__(64) void khead(const float* __restrict__ f,
                                            const float* __restrict__ inputs,
                                            const float* __restrict__ ow1,
                                            const float* __restrict__ ob1,
                                            const float* __restrict__ ow2,
                                            const float* __restrict__ ob2,
                                            float* __restrict__ out) {
    int bn = blockIdx.x;
    int c = threadIdx.x;
    float a = ob1[c];
    for (int k = 0; k < HD; k++) a += f[bn * HD + k] * ow1[k * 64 + c];
    float v = swishf(a) * ow2[c];
#pragma unroll
    for (int off = 32; off > 0; off >>= 1) v += __shfl_down(v, off);
    if (c == 0) out[bn] = inputs[bn] + DTC * (v + ob2[0]);
}

extern "C" void kernel_launch(void* const* d_in, const int* in_sizes, int n_in,
                              void* d_out, int out_size, void* d_ws, size_t ws_size,
                              hipStream_t stream) {
    const float* inputs = (const float*)d_in[0];
    const float* params = (const float*)d_in[1];
    const float* grid   = (const float*)d_in[3];
    const float* emb_w1 = (const float*)d_in[4];
    const float* emb_b1 = (const float*)d_in[5];
    const float* emb_w2 = (const float*)d_in[6];
    const float* emb_b2 = (const float*)d_in[7];
    const float* mw1 = (const float*)d_in[8];
    const float* mb1 = (const float*)d_in[9];
    const float* mw2 = (const float*)d_in[10];
    const float* mb2 = (const float*)d_in[11];
    const float* uw1 = (const float*)d_in[12];
    const float* ub1 = (const float*)d_in[13];
    const float* uw2 = (const float*)d_in[14];
    const float* ub2 = (const float*)d_in[15];
    const float* ow1 = (const float*)d_in[16];
    const float* ob1 = (const float*)d_in[17];
    const float* ow2 = (const float*)d_in[18];
    const float* ob2 = (const float*)d_in[19];
    float* out = (float*)d_out;

    float* ws  = (float*)d_ws;
    float* pos = ws;                      // BS*NX*2
    float* sq  = pos + BSZ * NXN * 2;     // BS*NX
    float* f   = sq + BSZ * NXN;          // BS*NX*H
    float* fnew = f + BSZ * NXN * HD;     // BS*NX*H
    float* p1   = fnew + BSZ * NXN * HD;  // BS*8*H
    float* p2   = p1 + BSZ * 8 * HD;      // BS*8*H
    float* gmm  = p2 + BSZ * 8 * HD;      // 16
    int* idxw   = (int*)(gmm + 16);       // BS*NX*K ints
    unsigned short* mw1p = (unsigned short*)(idxw + NN * KNN);  // 6*33*1024
    unsigned short* mw2p = mw1p + 6 * 33 * 1024;                // 6*16*1024
    unsigned short* uw1p = mw2p + 6 * 16 * 1024;                // 6*33*1024
    unsigned short* uw2p = uw1p + 6 * 33 * 1024;                // 6*16*1024

    kminmax<<<BSZ, 256, 0, stream>>>(grid, gmm);
    kpos<<<NN / 256, 256, 0, stream>>>(grid, gmm, pos, sq);
    kknnW<<<BSZ * (NXN / 32), 256, 0, stream>>>(pos, sq, idxw);

    kpack<<<(6 * 33 * 1024 + 255) / 256, 256, 0, stream>>>(mw1, mw1p, 264, 33, 6);
    kpack<<<(6 * 16 * 1024 + 255) / 256, 256, 0, stream>>>(mw2, mw2p, 128, 16, 6);
    kpack<<<(6 * 33 * 1024 + 255) / 256, 256, 0, stream>>>(uw1, uw1p, 261, 33, 6);
    kpack<<<(6 * 16 * 1024 + 255) / 256, 256, 0, stream>>>(uw2, uw2p, 128, 16, 6);

    kembed<<<NN, 128, 0, stream>>>(inputs, pos, params,
                                   emb_w1, emb_b1, emb_w2, emb_b2, f);
    for (int l = 0; l < NLAY; l++) {
        kmsg2<<<NN / NPB, 256, 0, stream>>>(f, fnew, inputs, pos, params, idxw,
                                            mw1p + l * 33 * 1024, mw1 + l * 264 * HD, mb1 + l * HD,
                                            mw2p + l * 16 * 1024, mb2 + l * HD,
                                            uw1p + l * 33 * 1024, uw1 + l * 261 * HD, ub1 + l * HD,
                                            uw2p + l * 16 * 1024, ub2 + l * HD);
        kstats<<<BSZ * 8, 256, 0, stream>>>(fnew, p1, p2);
        kapply2<<<(BSZ * NXN * HD) / 256, 256, 0, stream>>>(fnew, p1, p2, f);
    }
    khead<<<NN, 64, 0, stream>>>(f, inputs, ow1, ob1, ow2, ob2, out);
}

// Round 5
// 1115.091 us; speedup vs baseline: 4.9332x; 1.0037x over previous
//
#include <hip/hip_runtime.h>
#include <math.h>

#define BSZ 4
#define NXN 4096
#define NPARP 5
#define HD 128
#define NLAY 6
#define KNN 16
#define DTC 0.1f
#define EPSC 1e-5f
#define NN (BSZ * NXN)
#define NPB 8          // nodes per block in kmsg3
#define EPB 128        // edges per block

typedef __attribute__((ext_vector_type(8))) short short8;
typedef __attribute__((ext_vector_type(4))) float f32x4;

#define XR(r) (((r) & 7) << 4)

// LDS byte offsets for kmsg3
#define OFF_E   0        // 128 x 256B  (fj bf16 -> h bf16)
#define OFF_AU  32768    // 16 x 512B   (update A: [fi | agg] bf16)
#define OFF_HU  40960    // 16 x 256B   (update hidden bf16)
#define OFF_DU  45056    // 128 f32
#define OFF_DPX 45568
#define OFF_DPY 46080
#define OFF_VAR 46592    // [8][8] f32
#define SMEMB   46848

__device__ __forceinline__ float swishf(float x) {
    return x / (1.0f + __expf(-x));
}

// round-to-nearest bf16 (weights only)
__device__ __forceinline__ unsigned short f2bf(float x) {
    union { float f; unsigned u; } v; v.f = x;
    unsigned r = v.u + 0x7fffu + ((v.u >> 16) & 1u);
    return (unsigned short)(r >> 16);
}
// truncation bf16 (activations; 1 VALU op)
__device__ __forceinline__ unsigned short trh(float x) {
    union { float f; unsigned u; } v; v.f = x;
    return (unsigned short)(v.u >> 16);
}

// ---------------- grid min/max per batch ----------------
__global__ void kminmax(const float* __restrict__ grid, float* __restrict__ gmm) {
    int b = blockIdx.x;
    int t = threadIdx.x;
    float mnx = 1e30f, mxx = -1e30f, mny = 1e30f, mxy = -1e30f;
    for (int n = t; n < NXN; n += 256) {
        float x = grid[(b * NXN + n) * 2 + 0];
        float y = grid[(b * NXN + n) * 2 + 1];
        mnx = fminf(mnx, x); mxx = fmaxf(mxx, x);
        mny = fminf(mny, y); mxy = fmaxf(mxy, y);
    }
    __shared__ float s[4][256];
    s[0][t] = mnx; s[1][t] = mxx; s[2][t] = mny; s[3][t] = mxy;
    __syncthreads();
    for (int off = 128; off > 0; off >>= 1) {
        if (t < off) {
            s[0][t] = fminf(s[0][t], s[0][t + off]);
            s[1][t] = fmaxf(s[1][t], s[1][t + off]);
            s[2][t] = fminf(s[2][t], s[2][t + off]);
            s[3][t] = fmaxf(s[3][t], s[3][t + off]);
        }
        __syncthreads();
    }
    if (t == 0) {
        gmm[b * 4 + 0] = s[0][0];
        gmm[b * 4 + 1] = s[1][0];
        gmm[b * 4 + 2] = s[2][0];
        gmm[b * 4 + 3] = s[3][0];
    }
}

// ---------------- pos + sq ----------------
__global__ void kpos(const float* __restrict__ grid, const float* __restrict__ gmm,
                     float* __restrict__ pos, float* __restrict__ sq) {
    int g = blockIdx.x * 256 + threadIdx.x;
    if (g >= NN) return;
    int b = g >> 12;
    float gx = grid[g * 2], gy = grid[g * 2 + 1];
    float px = (gx - gmm[b * 4 + 0]) / (gmm[b * 4 + 1] - gmm[b * 4 + 0]);
    float py = (gy - gmm[b * 4 + 2]) / (gmm[b * 4 + 3] - gmm[b * 4 + 2]);
    pos[g * 2] = px; pos[g * 2 + 1] = py;
    sq[g] = __fadd_rn(__fmul_rn(px, px), __fmul_rn(py, py));
}

// ---------------- KNN: one wave per node, chunked LDS, 16 extraction rounds ----
// lane L owns candidates q = c*16+tt  <->  j = c*1024 + tt*64 + L
__global__ __launch_bounds__(256) void kknnC(const float* __restrict__ pos,
                                             const float* __restrict__ sq,
                                             int* __restrict__ idxw) {
    __shared__ float2 sxy[1024];
    __shared__ float ssq[1024];
    int blk = blockIdx.x;           // 4096 blocks; 1024 per batch
    int b = blk >> 10;
    int t = threadIdx.x;
    int lane = t & 63, w = t >> 6;
    int i = (blk & 1023) * 4 + w;   // node within batch (one per wave)
    float2 pi = *(const float2*)&pos[(b * NXN + i) * 2];
    float sqi = sq[b * NXN + i];
    float pk[64];
    float g[4];
#pragma unroll
    for (int c = 0; c < 4; ++c) {
        __syncthreads();            // protect LDS buffer reuse
        for (int n = t; n < 1024; n += 256) {
            int j = b * NXN + c * 1024 + n;
            sxy[n] = *(const float2*)&pos[j * 2];
            ssq[n] = sq[j];
        }
        __syncthreads();
        float gc = 1e38f;
#pragma unroll
        for (int tt = 0; tt < 16; ++tt) {
            int n = tt * 64 + lane;
            float2 pj = sxy[n];
            float dot = fmaf(pi.x, pj.x, pi.y * pj.y);
            float d2 = (sqi + ssq[n]) - 2.0f * dot;
            d2 = (c * 1024 + n == i) ? 1e38f : d2;
            pk[c * 16 + tt] = d2;
            gc = fminf(gc, d2);
        }
        g[c] = gc;
    }
    int obase = (b * NXN + i) * KNN;
#pragma unroll 1
    for (int r = 0; r < KNN; ++r) {
        float m = fminf(fminf(g[0], g[1]), fminf(g[2], g[3]));
        float gm = m;
#pragma unroll
        for (int off = 1; off < 64; off <<= 1)
            gm = fminf(gm, __shfl_xor(gm, off));
        if (m == gm) {              // winner lane(s) only
            int jt = 0;
            if (g[0] == gm) {
                float ng = 1e38f;
#pragma unroll
                for (int tt = 0; tt < 16; ++tt) {
                    bool hit = (pk[tt] == gm);
                    jt = hit ? tt : jt;
                    pk[tt] = hit ? 1e38f : pk[tt];
                    ng = fminf(ng, pk[tt]);
                }
                g[0] = ng;
            }
            if (g[1] == gm) {
                float ng = 1e38f;
#pragma unroll
                for (int tt = 16; tt < 32; ++tt) {
                    bool hit = (pk[tt] == gm);
                    jt = hit ? tt : jt;
                    pk[tt] = hit ? 1e38f : pk[tt];
                    ng = fminf(ng, pk[tt]);
                }
                g[1] = ng;
            }
            if (g[2] == gm) {
                float ng = 1e38f;
#pragma unroll
                for (int tt = 32; tt < 48; ++tt) {
                    bool hit = (pk[tt] == gm);
                    jt = hit ? tt : jt;
                    pk[tt] = hit ? 1e38f : pk[tt];
                    ng = fminf(ng, pk[tt]);
                }
                g[2] = ng;
            }
            if (g[3] == gm) {
                float ng = 1e38f;
#pragma unroll
                for (int tt = 48; tt < 64; ++tt) {
                    bool hit = (pk[tt] == gm);
                    jt = hit ? tt : jt;
                    pk[tt] = hit ? 1e38f : pk[tt];
                    ng = fminf(ng, pk[tt]);
                }
                g[3] = ng;
            }
            idxw[obase + r] = ((jt >> 4) << 10) + ((jt & 15) << 6) + lane;
        }
    }
}

// ---------------- weight pack: W[K x 128] f32 -> bf16 [ceil8(K)][128][8] ----------------
__global__ void kpack(const float* __restrict__ src, unsigned short* __restrict__ dst,
                      int K, int KB, int nmat) {
    int g = blockIdx.x * 256 + threadIdx.x;
    int per = KB * 1024;
    if (g >= nmat * per) return;
    int mat = g / per, rem = g % per;
    int kb = rem >> 10, r2 = rem & 1023;
    int n = r2 >> 3, j = r2 & 7;
    int k = kb * 8 + j;
    float v = (k < K) ? src[(mat * K + k) * HD + n] : 0.0f;
    dst[g] = f2bf(v);
}

// ---------------- embedding MLP ----------------
__global__ __launch_bounds__(128) void kembed(const float* __restrict__ inputs,
                                              const float* __restrict__ pos,
                                              const float* __restrict__ params,
                                              const float* __restrict__ w1,
                                              const float* __restrict__ b1,
                                              const float* __restrict__ w2,
                                              const float* __restrict__ b2,
                                              float* __restrict__ f,
                                              unsigned short* __restrict__ fh) {
    __shared__ __align__(16) float sh[HD];
    int t = threadIdx.x;
    int g = blockIdx.x;
    float rw1[8];
#pragma unroll
    for (int k = 0; k < 8; k++) rw1[k] = w1[k * HD + t];
    float u = inputs[g];
    float px = pos[g * 2], py = pos[g * 2 + 1];
    float a = b1[t] + u * rw1[0] + px * rw1[1] + py * rw1[2];
#pragma unroll
    for (int j = 0; j < NPARP; j++) a += params[g * NPARP + j] * rw1[3 + j];
    sh[t] = swishf(a);
    __syncthreads();
    float a2 = b2[t];
    for (int k = 0; k < HD; k += 4) {
        float4 s4 = *(const float4*)&sh[k];
        a2 = fmaf(s4.x, w2[(k + 0) * HD + t], a2);
        a2 = fmaf(s4.y, w2[(k + 1) * HD + t], a2);
        a2 = fmaf(s4.z, w2[(k + 2) * HD + t], a2);
        a2 = fmaf(s4.w, w2[(k + 3) * HD + t], a2);
    }
    float fv = swishf(a2);
    f[g * HD + t] = fv;
    fh[g * HD + t] = trh(fv);
}

// ---------------- fused MFMA layer, zero barriers, 2 nodes per wave ----------------
__global__ __launch_bounds__(256, 3) void kmsg3(
    const float* __restrict__ f, const unsigned short* __restrict__ fh,
    float* __restrict__ fnew,
    const float* __restrict__ inputs, const float* __restrict__ pos,
    const float* __restrict__ params, const int* __restrict__ idxw,
    const unsigned short* __restrict__ W1p, const float* __restrict__ W1r,
    const float* __restrict__ B1,
    const unsigned short* __restrict__ W2p, const float* __restrict__ B2,
    const unsigned short* __restrict__ U1p, const float* __restrict__ U1r,
    const float* __restrict__ UB1,
    const unsigned short* __restrict__ U2p, const float* __restrict__ UB2) {
    __shared__ __align__(16) char sm[SMEMB];
    int tid = threadIdx.x;
    int lane = tid & 63, w = tid >> 6;
    int l15 = lane & 15, l4 = lane >> 4;
    int bn0 = blockIdx.x * NPB;
    int base = bn0 & ~(NXN - 1);
    int r0 = w * 32;
    int ndA = 2 * w, ndB = 2 * w + 1;
    bool hiSel = (w & 1);
    int srcl = ((w >> 1) << 4) | l15;

    // ---- wave-local staging (no block barriers anywhere) ----
    if (lane < 32) {               // du/dpx/dpy for this wave's 32 edges
        int e = r0 + lane;
        int nd = e >> 4;
        int gj = idxw[(bn0 + nd) * KNN + (e & 15)];
        int gn = base + gj;
        ((float*)(sm + OFF_DU))[e]  = inputs[bn0 + nd] - inputs[gn];
        ((float*)(sm + OFF_DPX))[e] = pos[(bn0 + nd) * 2]     - pos[gn * 2];
        ((float*)(sm + OFF_DPY))[e] = pos[(bn0 + nd) * 2 + 1] - pos[gn * 2 + 1];
    } else if (lane < 42) {        // var for this wave's 2 nodes
        int q = lane - 32;
        int nd = ndA + q / 5, j = q % 5;
        ((float*)(sm + OFF_VAR))[nd * 8 + j] = params[(bn0 + nd) * NPARP + j];
    }
    {   // fi rows ndA/ndB -> sAU (bf16 copy)
        int r = ndA + (lane >> 5);
        int c4 = (lane & 31) * 4;
        uint2 v = *(const uint2*)&fh[(bn0 + r) * HD + c4];
        *(uint2*)(sm + OFF_AU + r * 512 + ((c4 * 2) ^ XR(r))) = v;
    }
    {   // gather fj rows r0..r0+31 (pure bf16 copy, swizzled)
        int r = r0 + (lane >> 1), hf = lane & 1;
        int gj = idxw[(bn0 + (r >> 4)) * KNN + (r & 15)];
        const uint4* src = (const uint4*)&fh[(base + gj) * HD + hf * 64];
        char* drow = sm + OFF_E + r * 256;
#pragma unroll
        for (int jj = 0; jj < 8; ++jj) {
            uint4 p = src[jj];
            *(uint4*)(drow + ((hf * 128 + jj * 16) ^ XR(r))) = p;
        }
    }
    // All LDS data consumed below was produced by THIS wave (in-order DS pipe);
    // A-frag rows belonging to other waves are read but their D rows discarded.

    // ---- hoists
    float duR[2][4], dpxR[2][4], dpyR[2][4];
#pragma unroll
    for (int mt = 0; mt < 2; ++mt)
#pragma unroll
        for (int reg = 0; reg < 4; ++reg) {
            int rr = r0 + mt * 16 + l4 * 4 + reg;
            duR[mt][reg]  = ((float*)(sm + OFF_DU))[rr];
            dpxR[mt][reg] = ((float*)(sm + OFF_DPX))[rr];
            dpyR[mt][reg] = ((float*)(sm + OFF_DPY))[rr];
        }
    float varA[5], varB[5];
#pragma unroll
    for (int j = 0; j < 5; ++j) {
        varA[j] = ((float*)(sm + OFF_VAR))[ndA * 8 + j];
        varB[j] = ((float*)(sm + OFF_VAR))[ndB * 8 + j];
    }

    // ---- message pass: com (fi@W1[0:128]) folded with mm1 (fj@W1[128:256]) ----
    {
        short8 afi[4];
#pragma unroll
        for (int k = 0; k < 4; ++k)
            afi[k] = *(short8*)(sm + OFF_AU + l15 * 512 + ((k * 64 + l4 * 16) ^ XR(l15)));
        short8 a0_[4], a1_[4];
#pragma unroll
        for (int k = 0; k < 4; ++k) {
            int ra = r0 + l15;
            a0_[k] = *(short8*)(sm + OFF_E + ra * 256 + ((k * 64 + l4 * 16) ^ XR(ra)));
            int rb = r0 + 16 + l15;
            a1_[k] = *(short8*)(sm + OFF_E + rb * 256 + ((k * 64 + l4 * 16) ^ XR(rb)));
        }
#pragma unroll 2
        for (int nt = 0; nt < 8; ++nt) {
            int col = nt * 16 + l15;
            // com chain (independent of mm1 chains)
            f32x4 accC = {0.f, 0.f, 0.f, 0.f};
#pragma unroll
            for (int k = 0; k < 4; ++k) {
                short8 bfr = *(const short8*)&W1p[((k * 4 + l4) * HD + col) * 8];
                accC = __builtin_amdgcn_mfma_f32_16x16x32_bf16(afi[k], bfr, accC, 0, 0, 0);
            }
            // mm1 chains for both nodes
            f32x4 accA = {0.f, 0.f, 0.f, 0.f};
            f32x4 accB = {0.f, 0.f, 0.f, 0.f};
#pragma unroll
            for (int k = 0; k < 4; ++k) {
                short8 bw = *(const short8*)&W1p[((16 + k * 4 + l4) * HD + col) * 8];
                accA = __builtin_amdgcn_mfma_f32_16x16x32_bf16(a0_[k], bw, accA, 0, 0, 0);
                accB = __builtin_amdgcn_mfma_f32_16x16x32_bf16(a1_[k], bw, accB, 0, 0, 0);
            }
            float lo = hiSel ? accC[2] : accC[0];
            float hi = hiSel ? accC[3] : accC[1];
            float vA = __shfl(lo, srcl);
            float vB = __shfl(hi, srcl);
            float bb = B1[col];
            float cA = bb, cB = bb;
#pragma unroll
            for (int j = 0; j < 5; ++j) {
                float wv = W1r[(259 + j) * HD + col];
                cA = fmaf(varA[j], wv, cA);
                cB = fmaf(varB[j], wv, cB);
            }
            cA += vA; cB += vB;
            float wdu = W1r[256 * HD + col];
            float wdx = W1r[257 * HD + col];
            float wdy = W1r[258 * HD + col];
#pragma unroll
            for (int reg = 0; reg < 4; ++reg) {
                int rrA = r0 + l4 * 4 + reg;
                float hvA = accA[reg] + cA + duR[0][reg] * wdu
                          + dpxR[0][reg] * wdx + dpyR[0][reg] * wdy;
                *(unsigned short*)(sm + OFF_E + rrA * 256 + ((col * 2) ^ XR(rrA))) =
                    trh(swishf(hvA));
                int rrB = r0 + 16 + l4 * 4 + reg;
                float hvB = accB[reg] + cB + duR[1][reg] * wdu
                          + dpxR[1][reg] * wdx + dpyR[1][reg] * wdy;
                *(unsigned short*)(sm + OFF_E + rrB * 256 + ((col * 2) ^ XR(rrB))) =
                    trh(swishf(hvB));
            }
        }
    }

    // ---- mm2 + mean -> agg into sAU cols 128..255 (wave-local) ----
    {
        short8 h0_[4], h1_[4];
#pragma unroll
        for (int k = 0; k < 4; ++k) {
            int ra = r0 + l15;
            h0_[k] = *(short8*)(sm + OFF_E + ra * 256 + ((k * 64 + l4 * 16) ^ XR(ra)));
            int rb = r0 + 16 + l15;
            h1_[k] = *(short8*)(sm + OFF_E + rb * 256 + ((k * 64 + l4 * 16) ^ XR(rb)));
        }
#pragma unroll 2
        for (int nt = 0; nt < 8; ++nt) {
            int col = nt * 16 + l15;
            float b2c = B2[col];
            f32x4 accA = {0.f, 0.f, 0.f, 0.f};
            f32x4 accB = {0.f, 0.f, 0.f, 0.f};
#pragma unroll
            for (int k = 0; k < 4; ++k) {
                short8 bw = *(const short8*)&W2p[((k * 4 + l4) * HD + col) * 8];
                accA = __builtin_amdgcn_mfma_f32_16x16x32_bf16(h0_[k], bw, accA, 0, 0, 0);
                accB = __builtin_amdgcn_mfma_f32_16x16x32_bf16(h1_[k], bw, accB, 0, 0, 0);
            }
            float sA = swishf(accA[0] + b2c) + swishf(accA[1] + b2c)
                     + swishf(accA[2] + b2c) + swishf(accA[3] + b2c);
            float sB = swishf(accB[0] + b2c) + swishf(accB[1] + b2c)
                     + swishf(accB[2] + b2c) + swishf(accB[3] + b2c);
            sA += __shfl_xor(sA, 16); sA += __shfl_xor(sA, 32);
            sB += __shfl_xor(sB, 16); sB += __shfl_xor(sB, 32);
            if (lane < 16) {
                int cb = 256 + (nt * 16 + lane) * 2;
                *(unsigned short*)(sm + OFF_AU + ndA * 512 + (cb ^ XR(ndA))) =
                    trh(sA * 0.0625f);
                *(unsigned short*)(sm + OFF_AU + ndB * 512 + (cb ^ XR(ndB))) =
                    trh(sB * 0.0625f);
            }
        }
    }

    // ---- update MLP stage 1: K=256 ([fi|agg]) -> swish -> sHU rows ndA/ndB ----
    {
        short8 au[8];
#pragma unroll
        for (int k = 0; k < 8; ++k)
            au[k] = *(short8*)(sm + OFF_AU + l15 * 512 + ((k * 64 + l4 * 16) ^ XR(l15)));
#pragma unroll 2
        for (int nt = 0; nt < 8; ++nt) {
            int col = nt * 16 + l15;
            f32x4 acc = {0.f, 0.f, 0.f, 0.f};
#pragma unroll
            for (int k = 0; k < 8; ++k) {
                short8 bw = *(const short8*)&U1p[((k * 4 + l4) * HD + col) * 8];
                acc = __builtin_amdgcn_mfma_f32_16x16x32_bf16(au[k], bw, acc, 0, 0, 0);
            }
            float hA = hiSel ? acc[2] : acc[0];
            float hB = hiSel ? acc[3] : acc[1];
            float iv = UB1[col];
            float ivA = iv, ivB = iv;
#pragma unroll
            for (int j = 0; j < 5; ++j) {
                float wv = U1r[(256 + j) * HD + col];
                ivA = fmaf(varA[j], wv, ivA);
                ivB = fmaf(varB[j], wv, ivB);
            }
            hA = swishf(hA + ivA);
            hB = swishf(hB + ivB);
            if (l4 == (w >> 1)) {
                *(unsigned short*)(sm + OFF_HU + ndA * 256 + ((col * 2) ^ XR(ndA))) = trh(hA);
                *(unsigned short*)(sm + OFF_HU + ndB * 256 + ((col * 2) ^ XR(ndB))) = trh(hB);
            }
        }
    }

    // ---- update MLP stage 2: K=128 -> residual -> fnew ----
    {
        short8 ah[4];
#pragma unroll
        for (int k = 0; k < 4; ++k)
            ah[k] = *(short8*)(sm + OFF_HU + l15 * 256 + ((k * 64 + l4 * 16) ^ XR(l15)));
#pragma unroll 2
        for (int nt = 0; nt < 8; ++nt) {
            int col = nt * 16 + l15;
            f32x4 acc = {0.f, 0.f, 0.f, 0.f};
#pragma unroll
            for (int k = 0; k < 4; ++k) {
                short8 bw = *(const short8*)&U2p[((k * 4 + l4) * HD + col) * 8];
                acc = __builtin_amdgcn_mfma_f32_16x16x32_bf16(ah[k], bw, acc, 0, 0, 0);
            }
            float oA = hiSel ? acc[2] : acc[0];
            float oB = hiSel ? acc[3] : acc[1];
            float ub = UB2[col];
            if (l4 == (w >> 1)) {
                int giA = (bn0 + ndA) * HD + col;
                fnew[giA] = f[giA] + swishf(oA + ub);
                int giB = (bn0 + ndB) * HD + col;
                fnew[giB] = f[giB] + swishf(oB + ub);
            }
        }
    }
}

// ---------------- instance norm: stats (128 blocks) + fused finalize/apply ----------------
__global__ __launch_bounds__(256) void kstats(const float* __restrict__ fnew,
                                              float* __restrict__ p1, float* __restrict__ p2) {
    int blk = blockIdx.x;           // BSZ*32
    int b = blk >> 5;
    int ch = blk & 31;
    int t = threadIdx.x;
    int c = t & 127;
    int half = t >> 7;
    int nbase = ch * 128;
    float s1 = 0.0f, s2 = 0.0f;
    for (int n = half; n < 128; n += 2) {
        float v = fnew[((b * NXN) + (nbase + n)) * HD + c];
        s1 += v; s2 += v * v;
    }
    __shared__ float r1[256], r2[256];
    r1[t] = s1; r2[t] = s2;
    __syncthreads();
    if (half == 0) {
        s1 += r1[t + 128]; s2 += r2[t + 128];
        p1[blk * HD + c] = s1;
        p2[blk * HD + c] = s2;
    }
}

__global__ void kapply2(const float* __restrict__ fnew,
                        const float* __restrict__ p1, const float* __restrict__ p2,
                        float* __restrict__ f, unsigned short* __restrict__ fh) {
    int g = blockIdx.x * 256 + threadIdx.x;
    int b = g >> 19;
    int c = g & 127;
    float s1 = 0.0f, s2 = 0.0f;
#pragma unroll
    for (int ch = 0; ch < 32; ch++) {
        s1 += p1[(b * 32 + ch) * HD + c];
        s2 += p2[(b * 32 + ch) * HD + c];
    }
    float m = s1 * (1.0f / NXN);
    float v = s2 * (1.0f / NXN) - m * m;
    float fv = (fnew[g] - m) * rsqrtf(v + EPSC);
    f[g] = fv;
    fh[g] = trh(fv);
}

// ---------------- output head ----------------
__global__ __launch_bounds__(64) void khead(const float* __restrict__ f,
                                            const float* __restrict__ inputs,
                                            const float* __restrict__ ow1,
                                            const float* __restrict__ ob1,
                                            const float* __restrict__ ow2,
                                            const float* __restrict__ ob2,
                                            float* __restrict__ out) {
    int bn = blockIdx.x;
    int c = threadIdx.x;
    float a = ob1[c];
    for (int k = 0; k < HD; k++) a += f[bn * HD + k] * ow1[k * 64 + c];
    float v = swishf(a) * ow2[c];
#pragma unroll
    for (int off = 32; off > 0; off >>= 1) v += __shfl_down(v, off);
    if (c == 0) out[bn] = inputs[bn] + DTC * (v + ob2[0]);
}

extern "C" void kernel_launch(void* const* d_in, const int* in_sizes, int n_in,
                              void* d_out, int out_size, void* d_ws, size_t ws_size,
                              hipStream_t stream) {
    const float* inputs = (const float*)d_in[0];
    const float* params = (const float*)d_in[1];
    const float* grid   = (const float*)d_in[3];
    const float* emb_w1 = (const float*)d_in[4];
    const float* emb_b1 = (const float*)d_in[5];
    const float* emb_w2 = (const float*)d_in[6];
    const float* emb_b2 = (const float*)d_in[7];
    const float* mw1 = (const float*)d_in[8];
    const float* mb1 = (const float*)d_in[9];
    const float* mw2 = (const float*)d_in[10];
    const float* mb2 = (const float*)d_in[11];
    const float* uw1 = (const float*)d_in[12];
    const float* ub1 = (const float*)d_in[13];
    const float* uw2 = (const float*)d_in[14];
    const float* ub2 = (const float*)d_in[15];
    const float* ow1 = (const float*)d_in[16];
    const float* ob1 = (const float*)d_in[17];
    const float* ow2 = (const float*)d_in[18];
    const float* ob2 = (const float*)d_in[19];
    float* out = (float*)d_out;

    float* ws  = (float*)d_ws;
    float* pos = ws;                      // BS*NX*2
    float* sq  = pos + BSZ * NXN * 2;     // BS*NX
    float* f   = sq + BSZ * NXN;          // BS*NX*H
    float* fnew = f + BSZ * NXN * HD;     // BS*NX*H
    float* p1   = fnew + BSZ * NXN * HD;  // BS*32*H
    float* p2   = p1 + BSZ * 32 * HD;     // BS*32*H
    float* gmm  = p2 + BSZ * 32 * HD;     // 16
    int* idxw   = (int*)(gmm + 16);       // BS*NX*K ints
    unsigned short* mw1p = (unsigned short*)(idxw + NN * KNN);  // 6*33*1024
    unsigned short* mw2p = mw1p + 6 * 33 * 1024;                // 6*16*1024
    unsigned short* uw1p = mw2p + 6 * 16 * 1024;                // 6*33*1024
    unsigned short* uw2p = uw1p + 6 * 33 * 1024;                // 6*16*1024
    unsigned short* fh   = uw2p + 6 * 16 * 1024;                // BS*NX*H bf16

    kminmax<<<BSZ, 256, 0, stream>>>(grid, gmm);
    kpos<<<NN / 256, 256, 0, stream>>>(grid, gmm, pos, sq);
    kknnC<<<BSZ * (NXN / 4), 256, 0, stream>>>(pos, sq, idxw);

    kpack<<<(6 * 33 * 1024 + 255) / 256, 256, 0, stream>>>(mw1, mw1p, 264, 33, 6);
    kpack<<<(6 * 16 * 1024 + 255) / 256, 256, 0, stream>>>(mw2, mw2p, 128, 16, 6);
    kpack<<<(6 * 33 * 1024 + 255) / 256, 256, 0, stream>>>(uw1, uw1p, 261, 33, 6);
    kpack<<<(6 * 16 * 1024 + 255) / 256, 256, 0, stream>>>(uw2, uw2p, 128, 16, 6);

    kembed<<<NN, 128, 0, stream>>>(inputs, pos, params,
                                   emb_w1, emb_b1, emb_w2, emb_b2, f, fh);
    for (int l = 0; l < NLAY; l++) {
        kmsg3<<<NN / NPB, 256, 0, stream>>>(f, fh, fnew, inputs, pos, params, idxw,
                                            mw1p + l * 33 * 1024, mw1 + l * 264 * HD, mb1 + l * HD,
                                            mw2p + l * 16 * 1024, mb2 + l * HD,
                                            uw1p + l * 33 * 1024, uw1 + l * 261 * HD, ub1 + l * HD,
                                            uw2p + l * 16 * 1024, ub2 + l * HD);
        kstats<<<BSZ * 32, 256, 0, stream>>>(fnew, p1, p2);
        kapply2<<<(BSZ * NXN * HD) / 256, 256, 0, stream>>>(fnew, p1, p2, f, fh);
    }
    khead<<<NN, 64, 0, stream>>>(f, inputs, ow1, ob1, ow2, ob2, out);
}

// Round 6
// 695.090 us; speedup vs baseline: 7.9140x; 1.6042x over previous
//
#include <hip/hip_runtime.h>
#include <math.h>

#define BSZ 4
#define NXN 4096
#define NPARP 5
#define HD 128
#define NLAY 6
#define KNN 16
#define DTC 0.1f
#define EPSC 1e-5f
#define NN (BSZ * NXN)
#define NPB 8          // nodes per block in kmsg4
#define EPB 128        // edges per block

typedef __attribute__((ext_vector_type(8))) short short8;
typedef __attribute__((ext_vector_type(4))) float f32x4;

#define XR(r) (((r) & 7) << 4)

// LDS byte offsets for kmsg4
#define OFF_E   0        // 128 x 256B  (fj bf16 -> h bf16)
#define OFF_AU  32768    // 16 x 512B   (update A: [fi | agg] bf16)
#define OFF_HU  40960    // 16 x 256B   (update hidden bf16)
#define OFF_DU  45056    // 128 f32
#define OFF_DPX 45568
#define OFF_DPY 46080
#define OFF_VAR 46592    // [8][8] f32
#define SMEMB   46848

__device__ __forceinline__ float swishf(float x) {
    return x / (1.0f + __expf(-x));
}

// round-to-nearest bf16 (weights only)
__device__ __forceinline__ unsigned short f2bf(float x) {
    union { float f; unsigned u; } v; v.f = x;
    unsigned r = v.u + 0x7fffu + ((v.u >> 16) & 1u);
    return (unsigned short)(r >> 16);
}
// truncation bf16 (activations; 1 VALU op)
__device__ __forceinline__ unsigned short trh(float x) {
    union { float f; unsigned u; } v; v.f = x;
    return (unsigned short)(v.u >> 16);
}

// ---------------- grid min/max per batch ----------------
__global__ void kminmax(const float* __restrict__ grid, float* __restrict__ gmm) {
    int b = blockIdx.x;
    int t = threadIdx.x;
    float mnx = 1e30f, mxx = -1e30f, mny = 1e30f, mxy = -1e30f;
    for (int n = t; n < NXN; n += 256) {
        float x = grid[(b * NXN + n) * 2 + 0];
        float y = grid[(b * NXN + n) * 2 + 1];
        mnx = fminf(mnx, x); mxx = fmaxf(mxx, x);
        mny = fminf(mny, y); mxy = fmaxf(mxy, y);
    }
    __shared__ float s[4][256];
    s[0][t] = mnx; s[1][t] = mxx; s[2][t] = mny; s[3][t] = mxy;
    __syncthreads();
    for (int off = 128; off > 0; off >>= 1) {
        if (t < off) {
            s[0][t] = fminf(s[0][t], s[0][t + off]);
            s[1][t] = fmaxf(s[1][t], s[1][t + off]);
            s[2][t] = fminf(s[2][t], s[2][t + off]);
            s[3][t] = fmaxf(s[3][t], s[3][t + off]);
        }
        __syncthreads();
    }
    if (t == 0) {
        gmm[b * 4 + 0] = s[0][0];
        gmm[b * 4 + 1] = s[1][0];
        gmm[b * 4 + 2] = s[2][0];
        gmm[b * 4 + 3] = s[3][0];
    }
}

// ---------------- pos + sq ----------------
__global__ void kpos(const float* __restrict__ grid, const float* __restrict__ gmm,
                     float* __restrict__ pos, float* __restrict__ sq) {
    int g = blockIdx.x * 256 + threadIdx.x;
    if (g >= NN) return;
    int b = g >> 12;
    float gx = grid[g * 2], gy = grid[g * 2 + 1];
    float px = (gx - gmm[b * 4 + 0]) / (gmm[b * 4 + 1] - gmm[b * 4 + 0]);
    float py = (gy - gmm[b * 4 + 2]) / (gmm[b * 4 + 3] - gmm[b * 4 + 2]);
    pos[g * 2] = px; pos[g * 2 + 1] = py;
    sq[g] = __fadd_rn(__fmul_rn(px, px), __fmul_rn(py, py));
}

// ---------------- KNN: one wave per node, chunked LDS, 16 extraction rounds ----
__global__ __launch_bounds__(256) void kknnC(const float* __restrict__ pos,
                                             const float* __restrict__ sq,
                                             int* __restrict__ idxw) {
    __shared__ float2 sxy[1024];
    __shared__ float ssq[1024];
    int blk = blockIdx.x;
    int b = blk >> 10;
    int t = threadIdx.x;
    int lane = t & 63, w = t >> 6;
    int i = (blk & 1023) * 4 + w;
    float2 pi = *(const float2*)&pos[(b * NXN + i) * 2];
    float sqi = sq[b * NXN + i];
    float pk[64];
    float g[4];
#pragma unroll
    for (int c = 0; c < 4; ++c) {
        __syncthreads();
        for (int n = t; n < 1024; n += 256) {
            int j = b * NXN + c * 1024 + n;
            sxy[n] = *(const float2*)&pos[j * 2];
            ssq[n] = sq[j];
        }
        __syncthreads();
        float gc = 1e38f;
#pragma unroll
        for (int tt = 0; tt < 16; ++tt) {
            int n = tt * 64 + lane;
            float2 pj = sxy[n];
            float dot = fmaf(pi.x, pj.x, pi.y * pj.y);
            float d2 = (sqi + ssq[n]) - 2.0f * dot;
            d2 = (c * 1024 + n == i) ? 1e38f : d2;
            pk[c * 16 + tt] = d2;
            gc = fminf(gc, d2);
        }
        g[c] = gc;
    }
    int obase = (b * NXN + i) * KNN;
#pragma unroll 1
    for (int r = 0; r < KNN; ++r) {
        float m = fminf(fminf(g[0], g[1]), fminf(g[2], g[3]));
        float gm = m;
#pragma unroll
        for (int off = 1; off < 64; off <<= 1)
            gm = fminf(gm, __shfl_xor(gm, off));
        if (m == gm) {
            int jt = 0;
            if (g[0] == gm) {
                float ng = 1e38f;
#pragma unroll
                for (int tt = 0; tt < 16; ++tt) {
                    bool hit = (pk[tt] == gm);
                    jt = hit ? tt : jt;
                    pk[tt] = hit ? 1e38f : pk[tt];
                    ng = fminf(ng, pk[tt]);
                }
                g[0] = ng;
            }
            if (g[1] == gm) {
                float ng = 1e38f;
#pragma unroll
                for (int tt = 16; tt < 32; ++tt) {
                    bool hit = (pk[tt] == gm);
                    jt = hit ? tt : jt;
                    pk[tt] = hit ? 1e38f : pk[tt];
                    ng = fminf(ng, pk[tt]);
                }
                g[1] = ng;
            }
            if (g[2] == gm) {
                float ng = 1e38f;
#pragma unroll
                for (int tt = 32; tt < 48; ++tt) {
                    bool hit = (pk[tt] == gm);
                    jt = hit ? tt : jt;
                    pk[tt] = hit ? 1e38f : pk[tt];
                    ng = fminf(ng, pk[tt]);
                }
                g[2] = ng;
            }
            if (g[3] == gm) {
                float ng = 1e38f;
#pragma unroll
                for (int tt = 48; tt < 64; ++tt) {
                    bool hit = (pk[tt] == gm);
                    jt = hit ? tt : jt;
                    pk[tt] = hit ? 1e38f : pk[tt];
                    ng = fminf(ng, pk[tt]);
                }
                g[3] = ng;
            }
            idxw[obase + r] = ((jt >> 4) << 10) + ((jt & 15) << 6) + lane;
        }
    }
}

// ---------------- weight pack: W[K x 128] f32 -> bf16 [ceil8(K)][128][8] ----------------
__global__ void kpack(const float* __restrict__ src, unsigned short* __restrict__ dst,
                      int K, int KB, int nmat) {
    int g = blockIdx.x * 256 + threadIdx.x;
    int per = KB * 1024;
    if (g >= nmat * per) return;
    int mat = g / per, rem = g % per;
    int kb = rem >> 10, r2 = rem & 1023;
    int n = r2 >> 3, j = r2 & 7;
    int k = kb * 8 + j;
    float v = (k < K) ? src[(mat * K + k) * HD + n] : 0.0f;
    dst[g] = f2bf(v);
}

// ---------------- embedding MLP ----------------
__global__ __launch_bounds__(128) void kembed(const float* __restrict__ inputs,
                                              const float* __restrict__ pos,
                                              const float* __restrict__ params,
                                              const float* __restrict__ w1,
                                              const float* __restrict__ b1,
                                              const float* __restrict__ w2,
                                              const float* __restrict__ b2,
                                              float* __restrict__ f,
                                              unsigned short* __restrict__ fh) {
    __shared__ __align__(16) float sh[HD];
    int t = threadIdx.x;
    int g = blockIdx.x;
    float rw1[8];
#pragma unroll
    for (int k = 0; k < 8; k++) rw1[k] = w1[k * HD + t];
    float u = inputs[g];
    float px = pos[g * 2], py = pos[g * 2 + 1];
    float a = b1[t] + u * rw1[0] + px * rw1[1] + py * rw1[2];
#pragma unroll
    for (int j = 0; j < NPARP; j++) a += params[g * NPARP + j] * rw1[3 + j];
    sh[t] = swishf(a);
    __syncthreads();
    float a2 = b2[t];
    for (int k = 0; k < HD; k += 4) {
        float4 s4 = *(const float4*)&sh[k];
        a2 = fmaf(s4.x, w2[(k + 0) * HD + t], a2);
        a2 = fmaf(s4.y, w2[(k + 1) * HD + t], a2);
        a2 = fmaf(s4.z, w2[(k + 2) * HD + t], a2);
        a2 = fmaf(s4.w, w2[(k + 3) * HD + t], a2);
    }
    float fv = swishf(a2);
    f[g * HD + t] = fv;
    fh[g * HD + t] = trh(fv);
}

// ---------------- fused MFMA layer: col-split waves, prefetched weights ----------------
__global__ __launch_bounds__(256, 3) void kmsg4(
    const float* __restrict__ f, const unsigned short* __restrict__ fh,
    float* __restrict__ fnew,
    const float* __restrict__ inputs, const float* __restrict__ pos,
    const float* __restrict__ params, const int* __restrict__ idxw,
    const unsigned short* __restrict__ W1p, const float* __restrict__ W1r,
    const float* __restrict__ B1,
    const unsigned short* __restrict__ W2p, const float* __restrict__ B2,
    const unsigned short* __restrict__ U1p, const float* __restrict__ U1r,
    const float* __restrict__ UB1,
    const unsigned short* __restrict__ U2p, const float* __restrict__ UB2) {
    __shared__ __align__(16) char sm[SMEMB];
    int tid = threadIdx.x;
    int lane = tid & 63, w = tid >> 6;
    int l15 = lane & 15, l4 = lane >> 4;
    int bn0 = blockIdx.x * NPB;
    int base = bn0 & ~(NXN - 1);
    int r0 = w * 32;
    int c0 = w * 32 + l15, c1 = c0 + 16;
    float* sVAR = (float*)(sm + OFF_VAR);

    // ---- early weight loads: com (kb 0..15) + mm1 (kb 16..31) + scalars
    short8 bC0[4], bC1[4], bM10[4], bM11[4];
#pragma unroll
    for (int k = 0; k < 4; ++k) {
        bC0[k]  = *(const short8*)&W1p[((k * 4 + l4) * HD + c0) * 8];
        bC1[k]  = *(const short8*)&W1p[((k * 4 + l4) * HD + c1) * 8];
        bM10[k] = *(const short8*)&W1p[((16 + k * 4 + l4) * HD + c0) * 8];
        bM11[k] = *(const short8*)&W1p[((16 + k * 4 + l4) * HD + c1) * 8];
    }
    float vB1_0 = B1[c0], vB1_1 = B1[c1];
    float wdu0 = W1r[256 * HD + c0], wdx0 = W1r[257 * HD + c0], wdy0 = W1r[258 * HD + c0];
    float wdu1 = W1r[256 * HD + c1], wdx1 = W1r[257 * HD + c1], wdy1 = W1r[258 * HD + c1];
    float wv0[5], wv1[5];
#pragma unroll
    for (int j = 0; j < 5; ++j) {
        wv0[j] = W1r[(259 + j) * HD + c0];
        wv1[j] = W1r[(259 + j) * HD + c1];
    }
    float vB2_0 = B2[c0], vB2_1 = B2[c1];

    // ---- staging
    if (lane < 32) {               // du/dpx/dpy for edges r0..r0+31
        int e = r0 + lane;
        int nd = e >> 4;
        int gj = idxw[(bn0 + nd) * KNN + (e & 15)];
        int gn = base + gj;
        ((float*)(sm + OFF_DU))[e]  = inputs[bn0 + nd] - inputs[gn];
        ((float*)(sm + OFF_DPX))[e] = pos[(bn0 + nd) * 2]     - pos[gn * 2];
        ((float*)(sm + OFF_DPY))[e] = pos[(bn0 + nd) * 2 + 1] - pos[gn * 2 + 1];
    } else if (lane < 42) {        // var for nodes 2w, 2w+1
        int q = lane - 32;
        int nd = 2 * w + q / 5, j = q % 5;
        sVAR[nd * 8 + j] = params[(bn0 + nd) * NPARP + j];
    }
    {   // fi rows 2w,2w+1 -> sAU
        int r = 2 * w + (lane >> 5);
        int c4 = (lane & 31) * 4;
        uint2 v = *(const uint2*)&fh[(bn0 + r) * HD + c4];
        *(uint2*)(sm + OFF_AU + r * 512 + ((c4 * 2) ^ XR(r))) = v;
    }
    {   // zero sAU rows 8..15 (wave w: rows 8+2w, 9+2w)
        int r = 8 + 2 * w + (lane >> 5);
        int cz = (lane & 31) * 16;
        uint4 z = {0, 0, 0, 0};
        *(uint4*)(sm + OFF_AU + r * 512 + cz) = z;
    }
    {   // zero sHU rows 8..15
        int r = 8 + 2 * w + (lane >> 5);
        int cz = (lane & 31) * 8;
        uint2 z = {0, 0};
        *(uint2*)(sm + OFF_HU + r * 256 + cz) = z;
    }
    {   // gather fj rows r0..r0+31
        int r = r0 + (lane >> 1), hf = lane & 1;
        int gj = idxw[(bn0 + (r >> 4)) * KNN + (r & 15)];
        const uint4* src = (const uint4*)&fh[(base + gj) * HD + hf * 64];
        char* drow = sm + OFF_E + r * 256;
#pragma unroll
        for (int jj = 0; jj < 8; ++jj) {
            uint4 p = src[jj];
            *(uint4*)(drow + ((hf * 128 + jj * 16) ^ XR(r))) = p;
        }
    }
    __syncthreads();               // B1: staging complete

    // ---- com GEMM (single M-tile of nodes, wave's 2 col-tiles)
    f32x4 cm0 = {0.f, 0.f, 0.f, 0.f}, cm1 = {0.f, 0.f, 0.f, 0.f};
    {
        short8 afi[4];
#pragma unroll
        for (int k = 0; k < 4; ++k)
            afi[k] = *(short8*)(sm + OFF_AU + l15 * 512 + ((k * 64 + l4 * 16) ^ XR(l15)));
#pragma unroll
        for (int k = 0; k < 4; ++k) {
            cm0 = __builtin_amdgcn_mfma_f32_16x16x32_bf16(afi[k], bC0[k], cm0, 0, 0, 0);
            cm1 = __builtin_amdgcn_mfma_f32_16x16x32_bf16(afi[k], bC1[k], cm1, 0, 0, 0);
        }
    }
    if (l4 < 2) {                  // fold bias + var terms (valid node rows only)
#pragma unroll
        for (int reg = 0; reg < 4; ++reg) {
            int nd = l4 * 4 + reg;
            float s0 = vB1_0, s1 = vB1_1;
#pragma unroll
            for (int j = 0; j < 5; ++j) {
                float vv = sVAR[nd * 8 + j];
                s0 = fmaf(vv, wv0[j], s0);
                s1 = fmaf(vv, wv1[j], s1);
            }
            cm0[reg] += s0; cm1[reg] += s1;
        }
    }

    // prefetch mm2 weights (complete during mm1)
    short8 bM20[4], bM21[4];
#pragma unroll
    for (int k = 0; k < 4; ++k) {
        bM20[k] = *(const short8*)&W2p[((k * 4 + l4) * HD + c0) * 8];
        bM21[k] = *(const short8*)&W2p[((k * 4 + l4) * HD + c1) * 8];
    }

    // ---- mm1: per-m-tile pipeline (read A[m+1] before barrier m, write h[m] after)
    short8 aC[4], aN[4];
#pragma unroll
    for (int k = 0; k < 4; ++k)
        aC[k] = *(short8*)(sm + OFF_E + l15 * 256 + ((k * 64 + l4 * 16) ^ XR(l15)));
#pragma unroll
    for (int m = 0; m < 8; ++m) {
        f32x4 h0 = {0.f, 0.f, 0.f, 0.f}, h1 = {0.f, 0.f, 0.f, 0.f};
#pragma unroll
        for (int k = 0; k < 4; ++k) {
            h0 = __builtin_amdgcn_mfma_f32_16x16x32_bf16(aC[k], bM10[k], h0, 0, 0, 0);
            h1 = __builtin_amdgcn_mfma_f32_16x16x32_bf16(aC[k], bM11[k], h1, 0, 0, 0);
        }
        if (m < 7) {
#pragma unroll
            for (int k = 0; k < 4; ++k)
                aN[k] = *(short8*)(sm + OFF_E + ((m + 1) * 16 + l15) * 256 +
                                   ((k * 64 + l4 * 16) ^ XR(l15)));
        }
        float com0 = __shfl(cm0[m & 3], ((m >> 2) << 4) | l15);
        float com1 = __shfl(cm1[m & 3], ((m >> 2) << 4) | l15);
        float4 duv = *(const float4*)(sm + OFF_DU  + (m * 16 + l4 * 4) * 4);
        float4 dxv = *(const float4*)(sm + OFF_DPX + (m * 16 + l4 * 4) * 4);
        float4 dyv = *(const float4*)(sm + OFF_DPY + (m * 16 + l4 * 4) * 4);
        __syncthreads();           // barrier m: all waves have read rows m (and m+1)
#pragma unroll
        for (int reg = 0; reg < 4; ++reg) {
            int rr = m * 16 + l4 * 4 + reg;
            float d_u = ((const float*)&duv)[reg];
            float d_x = ((const float*)&dxv)[reg];
            float d_y = ((const float*)&dyv)[reg];
            float hv0 = h0[reg] + com0 + d_u * wdu0 + d_x * wdx0 + d_y * wdy0;
            *(unsigned short*)(sm + OFF_E + rr * 256 + ((c0 * 2) ^ XR(rr))) =
                trh(swishf(hv0));
            float hv1 = h1[reg] + com1 + d_u * wdu1 + d_x * wdx1 + d_y * wdy1;
            *(unsigned short*)(sm + OFF_E + rr * 256 + ((c1 * 2) ^ XR(rr))) =
                trh(swishf(hv1));
        }
        if (m < 7) {
#pragma unroll
            for (int k = 0; k < 4; ++k) aC[k] = aN[k];
        }
    }
    __syncthreads();               // h complete

    // prefetch upd1 weights + scalars (complete during mm2)
    short8 bU10[8], bU11[8];
#pragma unroll
    for (int k = 0; k < 8; ++k) {
        bU10[k] = *(const short8*)&U1p[((k * 4 + l4) * HD + c0) * 8];
        bU11[k] = *(const short8*)&U1p[((k * 4 + l4) * HD + c1) * 8];
    }
    float vUB1_0 = UB1[c0], vUB1_1 = UB1[c1];
    float uv0[5], uv1[5];
#pragma unroll
    for (int j = 0; j < 5; ++j) {
        uv0[j] = U1r[(256 + j) * HD + c0];
        uv1[j] = U1r[(256 + j) * HD + c1];
    }

    // ---- mm2 + mean -> agg (wave's 2 col-tiles, all 8 m-tiles)
#pragma unroll
    for (int m = 0; m < 8; ++m) {
        short8 hf4[4];
#pragma unroll
        for (int k = 0; k < 4; ++k)
            hf4[k] = *(short8*)(sm + OFF_E + (m * 16 + l15) * 256 +
                                ((k * 64 + l4 * 16) ^ XR(l15)));
        f32x4 s0 = {0.f, 0.f, 0.f, 0.f}, s1 = {0.f, 0.f, 0.f, 0.f};
#pragma unroll
        for (int k = 0; k < 4; ++k) {
            s0 = __builtin_amdgcn_mfma_f32_16x16x32_bf16(hf4[k], bM20[k], s0, 0, 0, 0);
            s1 = __builtin_amdgcn_mfma_f32_16x16x32_bf16(hf4[k], bM21[k], s1, 0, 0, 0);
        }
        float sum0 = swishf(s0[0] + vB2_0) + swishf(s0[1] + vB2_0)
                   + swishf(s0[2] + vB2_0) + swishf(s0[3] + vB2_0);
        float sum1 = swishf(s1[0] + vB2_1) + swishf(s1[1] + vB2_1)
                   + swishf(s1[2] + vB2_1) + swishf(s1[3] + vB2_1);
        sum0 += __shfl_xor(sum0, 16); sum0 += __shfl_xor(sum0, 32);
        sum1 += __shfl_xor(sum1, 16); sum1 += __shfl_xor(sum1, 32);
        if (lane < 16) {
            int ca = w * 32 + lane;
            *(unsigned short*)(sm + OFF_AU + m * 512 + ((256 + ca * 2) ^ XR(m))) =
                trh(sum0 * 0.0625f);
            *(unsigned short*)(sm + OFF_AU + m * 512 + ((256 + (ca + 16) * 2) ^ XR(m))) =
                trh(sum1 * 0.0625f);
        }
    }
    __syncthreads();               // agg complete

    // prefetch upd2 weights (complete during upd1)
    short8 bU20[4], bU21[4];
#pragma unroll
    for (int k = 0; k < 4; ++k) {
        bU20[k] = *(const short8*)&U2p[((k * 4 + l4) * HD + c0) * 8];
        bU21[k] = *(const short8*)&U2p[((k * 4 + l4) * HD + c1) * 8];
    }
    float vUB2_0 = UB2[c0], vUB2_1 = UB2[c1];

    // ---- upd1: K=256 ([fi|agg]) -> swish -> sHU
    {
        short8 au[8];
#pragma unroll
        for (int k = 0; k < 8; ++k)
            au[k] = *(short8*)(sm + OFF_AU + l15 * 512 + ((k * 64 + l4 * 16) ^ XR(l15)));
        f32x4 u0 = {0.f, 0.f, 0.f, 0.f}, u1 = {0.f, 0.f, 0.f, 0.f};
#pragma unroll
        for (int k = 0; k < 8; ++k) {
            u0 = __builtin_amdgcn_mfma_f32_16x16x32_bf16(au[k], bU10[k], u0, 0, 0, 0);
            u1 = __builtin_amdgcn_mfma_f32_16x16x32_bf16(au[k], bU11[k], u1, 0, 0, 0);
        }
        if (l4 < 2) {
#pragma unroll
            for (int reg = 0; reg < 4; ++reg) {
                int nd = l4 * 4 + reg;
                float s0 = vUB1_0, s1 = vUB1_1;
#pragma unroll
                for (int j = 0; j < 5; ++j) {
                    float vv = sVAR[nd * 8 + j];
                    s0 = fmaf(vv, uv0[j], s0);
                    s1 = fmaf(vv, uv1[j], s1);
                }
                *(unsigned short*)(sm + OFF_HU + nd * 256 + ((c0 * 2) ^ XR(nd))) =
                    trh(swishf(u0[reg] + s0));
                *(unsigned short*)(sm + OFF_HU + nd * 256 + ((c1 * 2) ^ XR(nd))) =
                    trh(swishf(u1[reg] + s1));
            }
        }
    }
    __syncthreads();               // hu complete

    // ---- upd2: K=128 -> residual -> fnew
    {
        short8 ah[4];
#pragma unroll
        for (int k = 0; k < 4; ++k)
            ah[k] = *(short8*)(sm + OFF_HU + l15 * 256 + ((k * 64 + l4 * 16) ^ XR(l15)));
        f32x4 o0 = {0.f, 0.f, 0.f, 0.f}, o1 = {0.f, 0.f, 0.f, 0.f};
#pragma unroll
        for (int k = 0; k < 4; ++k) {
            o0 = __builtin_amdgcn_mfma_f32_16x16x32_bf16(ah[k], bU20[k], o0, 0, 0, 0);
            o1 = __builtin_amdgcn_mfma_f32_16x16x32_bf16(ah[k], bU21[k], o1, 0, 0, 0);
        }
        if (l4 < 2) {
#pragma unroll
            for (int reg = 0; reg < 4; ++reg) {
                int nd = l4 * 4 + reg;
                int gi0 = (bn0 + nd) * HD + c0;
                fnew[gi0] = f[gi0] + swishf(o0[reg] + vUB2_0);
                int gi1 = (bn0 + nd) * HD + c1;
                fnew[gi1] = f[gi1] + swishf(o1[reg] + vUB2_1);
            }
        }
    }
}

// ---------------- instance norm: stats, finalize, apply ----------------
__global__ __launch_bounds__(256) void kstats(const float* __restrict__ fnew,
                                              float* __restrict__ p1, float* __restrict__ p2) {
    int blk = blockIdx.x;           // BSZ*32
    int b = blk >> 5;
    int ch = blk & 31;
    int t = threadIdx.x;
    int c = t & 127;
    int half = t >> 7;
    int nbase = ch * 128;
    float s1 = 0.0f, s2 = 0.0f;
    for (int n = half; n < 128; n += 2) {
        float v = fnew[((b * NXN) + (nbase + n)) * HD + c];
        s1 += v; s2 += v * v;
    }
    __shared__ float r1[256], r2[256];
    r1[t] = s1; r2[t] = s2;
    __syncthreads();
    if (half == 0) {
        s1 += r1[t + 128]; s2 += r2[t + 128];
        p1[blk * HD + c] = s1;
        p2[blk * HD + c] = s2;
    }
}

__global__ void kfinal(const float* __restrict__ p1, const float* __restrict__ p2,
                       float* __restrict__ mean, float* __restrict__ inv) {
    int g = blockIdx.x * 256 + threadIdx.x;
    if (g >= BSZ * HD) return;
    int b = g >> 7;
    int c = g & 127;
    float s1 = 0.0f, s2 = 0.0f;
#pragma unroll
    for (int ch = 0; ch < 32; ch++) {
        s1 += p1[(b * 32 + ch) * HD + c];
        s2 += p2[(b * 32 + ch) * HD + c];
    }
    float m = s1 * (1.0f / NXN);
    float v = s2 * (1.0f / NXN) - m * m;
    mean[g] = m;
    inv[g] = rsqrtf(v + EPSC);
}

__global__ void kapply(const float* __restrict__ fnew,
                       const float* __restrict__ mean, const float* __restrict__ inv,
                       float* __restrict__ f, unsigned short* __restrict__ fh) {
    int g = blockIdx.x * 256 + threadIdx.x;
    int b = g >> 19;
    int c = g & 127;
    float fv = (fnew[g] - mean[b * HD + c]) * inv[b * HD + c];
    f[g] = fv;
    fh[g] = trh(fv);
}

// ---------------- output head ----------------
__global__ __launch_bounds__(64) void khead(const float* __restrict__ f,
                                            const float* __restrict__ inputs,
                                            const float* __restrict__ ow1,
                                            const float* __restrict__ ob1,
                                            const float* __restrict__ ow2,
                                            const float* __restrict__ ob2,
                                            float* __restrict__ out) {
    int bn = blockIdx.x;
    int c = threadIdx.x;
    float a = ob1[c];
    for (int k = 0; k < HD; k++) a += f[bn * HD + k] * ow1[k * 64 + c];
    float v = swishf(a) * ow2[c];
#pragma unroll
    for (int off = 32; off > 0; off >>= 1) v += __shfl_down(v, off);
    if (c == 0) out[bn] = inputs[bn] + DTC * (v + ob2[0]);
}

extern "C" void kernel_launch(void* const* d_in, const int* in_sizes, int n_in,
                              void* d_out, int out_size, void* d_ws, size_t ws_size,
                              hipStream_t stream) {
    const float* inputs = (const float*)d_in[0];
    const float* params = (const float*)d_in[1];
    const float* grid   = (const float*)d_in[3];
    const float* emb_w1 = (const float*)d_in[4];
    const float* emb_b1 = (const float*)d_in[5];
    const float* emb_w2 = (const float*)d_in[6];
    const float* emb_b2 = (const float*)d_in[7];
    const float* mw1 = (const float*)d_in[8];
    const float* mb1 = (const float*)d_in[9];
    const float* mw2 = (const float*)d_in[10];
    const float* mb2 = (const float*)d_in[11];
    const float* uw1 = (const float*)d_in[12];
    const float* ub1 = (const float*)d_in[13];
    const float* uw2 = (const float*)d_in[14];
    const float* ub2 = (const float*)d_in[15];
    const float* ow1 = (const float*)d_in[16];
    const float* ob1 = (const float*)d_in[17];
    const float* ow2 = (const float*)d_in[18];
    const float* ob2 = (const float*)d_in[19];
    float* out = (float*)d_out;

    float* ws  = (float*)d_ws;
    float* pos = ws;                      // BS*NX*2
    float* sq  = pos + BSZ * NXN * 2;     // BS*NX
    float* f   = sq + BSZ * NXN;          // BS*NX*H
    float* fnew = f + BSZ * NXN * HD;     // BS*NX*H
    float* p1   = fnew + BSZ * NXN * HD;  // BS*32*H
    float* p2   = p1 + BSZ * 32 * HD;     // BS*32*H
    float* meanw = p2 + BSZ * 32 * HD;    // BS*H
    float* invw  = meanw + BSZ * HD;      // BS*H
    float* gmm  = invw + BSZ * HD;        // 16
    int* idxw   = (int*)(gmm + 16);       // BS*NX*K ints
    unsigned short* mw1p = (unsigned short*)(idxw + NN * KNN);  // 6*33*1024
    unsigned short* mw2p = mw1p + 6 * 33 * 1024;                // 6*16*1024
    unsigned short* uw1p = mw2p + 6 * 16 * 1024;                // 6*33*1024
    unsigned short* uw2p = uw1p + 6 * 33 * 1024;                // 6*16*1024
    unsigned short* fh   = uw2p + 6 * 16 * 1024;                // BS*NX*H bf16

    kminmax<<<BSZ, 256, 0, stream>>>(grid, gmm);
    kpos<<<NN / 256, 256, 0, stream>>>(grid, gmm, pos, sq);
    kknnC<<<BSZ * (NXN / 4), 256, 0, stream>>>(pos, sq, idxw);

    kpack<<<(6 * 33 * 1024 + 255) / 256, 256, 0, stream>>>(mw1, mw1p, 264, 33, 6);
    kpack<<<(6 * 16 * 1024 + 255) / 256, 256, 0, stream>>>(mw2, mw2p, 128, 16, 6);
    kpack<<<(6 * 33 * 1024 + 255) / 256, 256, 0, stream>>>(uw1, uw1p, 261, 33, 6);
    kpack<<<(6 * 16 * 1024 + 255) / 256, 256, 0, stream>>>(uw2, uw2p, 128, 16, 6);

    kembed<<<NN, 128, 0, stream>>>(inputs, pos, params,
                                   emb_w1, emb_b1, emb_w2, emb_b2, f, fh);
    for (int l = 0; l < NLAY; l++) {
        kmsg4<<<NN / NPB, 256, 0, stream>>>(f, fh, fnew, inputs, pos, params, idxw,
                                            mw1p + l * 33 * 1024, mw1 + l * 264 * HD, mb1 + l * HD,
                                            mw2p + l * 16 * 1024, mb2 + l * HD,
                                            uw1p + l * 33 * 1024, uw1 + l * 261 * HD, ub1 + l * HD,
                                            uw2p + l * 16 * 1024, ub2 + l * HD);
        kstats<<<BSZ * 32, 256, 0, stream>>>(fnew, p1, p2);
        kfinal<<<2, 256, 0, stream>>>(p1, p2, meanw, invw);
        kapply<<<(BSZ * NXN * HD) / 256, 256, 0, stream>>>(fnew, meanw, invw, f, fh);
    }
    khead<<<NN, 64, 0, stream>>>(f, inputs, ow1, ob1, ow2, ob2, out);
}